// Round 10
// baseline (621.204 us; speedup 1.0000x reference)
//
#include <hip/hip_runtime.h>

#define EPS   1e-8f
#define LAMB  20.0f
#define NI    128
#define NR    48
#define NT    64
#define NW    100
#define ND    768

typedef unsigned int uint;
typedef unsigned short ushortt;
typedef __attribute__((ext_vector_type(8))) short short8;
typedef __attribute__((ext_vector_type(4))) float f32x4;

// ======================= ws layout (fast path) ===========================
// All big arrays are stored in MFMA *fragment order*:
//   frag[tile][dc32][lane][8]  (lane = quad*16 + l15; 512 ushorts per dc32)
// element (row, col) of the logical [rows][ND] matrix lives at
//   ((tile)*NC + col/32)*512 + (((col%32)/8)*16 + row%16)*8 + col%8
// so a wave's fragment load is base + lane*16 bytes: fully coalesced 1KB.
// floats: [0,6144) invQ, [6144,12544) invK, [12544,18688) nVi, [18688,25088) nVt
#define OFF_KHI  102400ULL      // bf16 frag [64][7][24][512] normalized K hi
#define OFF_KLO  11112448ULL
#define OFF_QHI  22122496ULL    // bf16 frag [128][3][24][512] normalized Q hi
#define OFF_QLO  31559680ULL
#define OFF_TVB  40996864ULL    // bf16 frag [64][7][24][512] TV rows
#define OFF_IVB  52006912ULL    // bf16 frag [128][3][24][512] IV rows
#define OFF_MH   61444096ULL    // bf16 frag [64][7][4][512] M=TV.TV^T hi (k-pad zero)
#define OFF_ML   63279104ULL
#define OFF_HH   65114112ULL    // bf16 frag [128][3][2][512] H=IV.IV^T hi (k-pad zero)
#define OFF_HL   65900544ULL
#define WS_NEED  66686976ULL

__device__ inline unsigned short f2bf(float f) {
    uint u = __float_as_uint(f);
    u = (u + 0x7fffu + ((u >> 16) & 1u)) >> 16;
    return (unsigned short)u;
}
__device__ inline float bf2f(unsigned short h) {
    return __uint_as_float((uint)h << 16);
}
__device__ inline void split_store(float4 v, ushortt* hp, ushortt* lp) {
    unsigned short h0 = f2bf(v.x), h1 = f2bf(v.y), h2 = f2bf(v.z), h3 = f2bf(v.w);
    float f0 = bf2f(h0), f1 = bf2f(h1), f2 = bf2f(h2), f3 = bf2f(h3);
    ushort4 H; H.x = h0; H.y = h1; H.z = h2; H.w = h3;
    ushort4 L2; L2.x = f2bf(v.x - f0); L2.y = f2bf(v.y - f1); L2.z = f2bf(v.z - f2); L2.w = f2bf(v.w - f3);
    *(ushort4*)hp = H;
    *(ushort4*)lp = L2;
}
// swizzled LDS element addresses (16B-block XOR swizzle)
__device__ inline int swzATT(int r, int w) {   // shATT[48][128]
    return r * 128 + ((((w >> 3) ^ (r & 7)) << 3) | (w & 7));
}
__device__ inline int swzATT2(int w, int r) {  // shATT2[112][64]
    return w * 64 + ((((r >> 3) ^ (w & 7)) << 3) | (r & 7));
}
__device__ inline float wredsum(float v) {
#pragma unroll
    for (int m = 1; m < 64; m <<= 1) v += __shfl_xor(v, m, 64);
    return v;
}
__device__ inline float wredmax(float v) {
#pragma unroll
    for (int m = 1; m < 64; m <<= 1) v = fmaxf(v, __shfl_xor(v, m, 64));
    return v;
}

// ======================= prep kernels ====================================
__global__ void nafs_norms(const float* __restrict__ imgQ,
                           const float* __restrict__ imgV,
                           const float* __restrict__ txtK,
                           const float* __restrict__ txtV,
                           float* __restrict__ ws) {
    int row  = blockIdx.x * 4 + (threadIdx.x >> 6);
    int lane = threadIdx.x & 63;
    const float* src;
    int inv;
    if (row < 6144)       { src = imgQ + (size_t)row * ND;           inv = 1; }
    else if (row < 12544) { src = txtK + (size_t)(row - 6144) * ND;  inv = 1; }
    else if (row < 18688) { src = imgV + (size_t)(row - 12544) * ND; inv = 0; }
    else                  { src = txtV + (size_t)(row - 18688) * ND; inv = 0; }
    float ss = 0.f;
#pragma unroll
    for (int j = 0; j < 3; ++j) {
        float4 v = *(const float4*)(src + j * 256 + lane * 4);
        ss += v.x * v.x + v.y * v.y + v.z * v.z + v.w * v.w;
    }
#pragma unroll
    for (int off = 32; off > 0; off >>= 1) ss += __shfl_down(ss, off, 64);
    if (lane == 0) {
        float n = sqrtf(ss);
        ws[row] = inv ? (1.0f / (n + EPS)) : n;
    }
}

// convert: one block = one 16-row tile; coalesced reads -> LDS fragment
// transpose -> contiguous 16B stores.
__global__ __launch_bounds__(256)
void nafs_convert(const float* __restrict__ txtK,
                  const float* __restrict__ imgQ,
                  const float* __restrict__ txtV,
                  const float* __restrict__ imgV,
                  const float* __restrict__ ws,
                  ushortt* __restrict__ khi, ushortt* __restrict__ klo,
                  ushortt* __restrict__ qhi, ushortt* __restrict__ qlo,
                  ushortt* __restrict__ tvb, ushortt* __restrict__ ivb) {
    __shared__ __align__(16) ushortt sH[24 * 512];
    __shared__ __align__(16) ushortt sL[24 * 512];
    const int blk = blockIdx.x;
    const int tid = threadIdx.x;

    const float* src;
    const float* scale = nullptr;   // per-row scale (K/Q) or null
    ushortt* dh;
    ushortt* dl = nullptr;          // lo output (K/Q) or null
    int rowbase, rowlimit;

    if (blk < 448) {                      // K: t*7+m
        int tile = blk, t = tile / 7, m = tile % 7;
        src = txtK + (size_t)t * NW * ND;
        scale = ws + 6144 + t * NW;
        dh = khi + (size_t)tile * 24 * 512;
        dl = klo + (size_t)tile * 24 * 512;
        rowbase = m * 16; rowlimit = NW;
    } else if (blk < 832) {               // Q: i*3+n
        int tile = blk - 448, i = tile / 3;
        src = imgQ + (size_t)i * NR * ND;
        scale = ws + i * NR;
        dh = qhi + (size_t)tile * 24 * 512;
        dl = qlo + (size_t)tile * 24 * 512;
        rowbase = (tile % 3) * 16; rowlimit = NR;
    } else if (blk < 1280) {              // TVB
        int tile = blk - 832, t = tile / 7, m = tile % 7;
        src = txtV + (size_t)t * NW * ND;
        dh = tvb + (size_t)tile * 24 * 512;
        rowbase = m * 16; rowlimit = NW;
    } else {                              // IVB
        int tile = blk - 1280, i = tile / 3;
        src = imgV + (size_t)i * NR * ND;
        dh = ivb + (size_t)tile * 24 * 512;
        rowbase = (tile % 3) * 16; rowlimit = NR;
    }

    // stage 1: 16 rows x 192 float4 = 3072 units, 12 per thread, coalesced reads
#pragma unroll
    for (int j = 0; j < 12; ++j) {
        int idx = tid + j * 256;          // 0..3071
        int l   = idx / 192;              // row within tile 0..15
        int c4  = idx % 192;              // float4 index within row
        int row = rowbase + l;
        int dc32 = c4 >> 3, quad = (c4 & 7) >> 1, j0 = (c4 & 1) * 4;
        int off  = dc32 * 512 + (quad * 16 + l) * 8 + j0;
        if (row < rowlimit) {
            float4 v = *(const float4*)(src + (size_t)row * ND + c4 * 4);
            if (scale) { float s = scale[row]; v.x *= s; v.y *= s; v.z *= s; v.w *= s; }
            if (dl) {
                split_store(v, &sH[off], &sL[off]);
            } else {
                ushort4 u; u.x = f2bf(v.x); u.y = f2bf(v.y); u.z = f2bf(v.z); u.w = f2bf(v.w);
                *(ushort4*)&sH[off] = u;
            }
        } else {
            ushort4 z; z.x = z.y = z.z = z.w = 0;
            *(ushort4*)&sH[off] = z;
            if (dl) *(ushort4*)&sL[off] = z;
        }
    }
    __syncthreads();
    // stage 2: contiguous 16B stores (1536 short8 units, 6 per thread)
#pragma unroll
    for (int j = 0; j < 6; ++j) {
        int idx = tid + j * 256;
        *(short8*)&dh[idx * 8] = *(short8*)&sH[idx * 8];
        if (dl) *(short8*)&dl[idx * 8] = *(short8*)&sL[idx * 8];
    }
}

// r10: gram_m + gram_h fused into one 832-block launch (one launch+tail
// saved; gram_h's old 128-block grid left half the GPU idle).
// blk < 448: M[t]=TVB@TVB^T row-tile (t,m), waves split n (n0=wv, n1=wv+4).
// blk >= 448: H[i]=IVB@IVB^T tile (i,m) [384 blocks], wave wv<3 handles n=wv.
__global__ void nafs_gram(const ushortt* __restrict__ tvb,
                          const ushortt* __restrict__ ivb,
                          ushortt* __restrict__ mh, ushortt* __restrict__ ml,
                          ushortt* __restrict__ hh, ushortt* __restrict__ hl) {
    const int blk = blockIdx.x;
    const int tid = threadIdx.x, wv = tid >> 6, lane = tid & 63;
    const int quad = lane >> 4, l15 = lane & 15;

    if (blk < 448) {
        const int t = blk / 7, m = blk % 7;
        const ushortt* base = tvb + (size_t)t * 7 * 24 * 512;
        ushortt* mhB = mh + (size_t)t * 7 * 4 * 512;
        ushortt* mlB = ml + (size_t)t * 7 * 4 * 512;

        const int n0 = wv, n1 = wv + 4;
        f32x4 c0 = (f32x4){0.f, 0.f, 0.f, 0.f};
        f32x4 c1 = (f32x4){0.f, 0.f, 0.f, 0.f};
        for (int dc32 = 0; dc32 < 24; ++dc32) {
            short8 av = *(const short8*)&base[((size_t)m * 24 + dc32) * 512 + lane * 8];
            short8 b0 = *(const short8*)&base[((size_t)n0 * 24 + dc32) * 512 + lane * 8];
            c0 = __builtin_amdgcn_mfma_f32_16x16x32_bf16(av, b0, c0, 0, 0, 0);
            if (n1 < 7) {
                short8 b1 = *(const short8*)&base[((size_t)n1 * 24 + dc32) * 512 + lane * 8];
                c1 = __builtin_amdgcn_mfma_f32_16x16x32_bf16(av, b1, c1, 0, 0, 0);
            }
        }
#pragma unroll
        for (int p = 0; p < 2; ++p) {
            int n = (p == 0) ? n0 : n1;
            if (n < 7) {
                f32x4 c = (p == 0) ? c0 : c1;
#pragma unroll
                for (int reg = 0; reg < 4; ++reg) {
                    int wc = n * 16 + l15;             // col (0..111)
                    int lrow = quad * 4 + reg;         // row%16 within tile m
                    float v = c[reg];
                    ushortt h = f2bf(v);
                    size_t fo = ((size_t)m * 4 + (wc >> 5)) * 512
                              + ((((wc >> 3) & 3) * 16 + lrow) * 8) + (wc & 7);
                    mhB[fo] = h;
                    mlB[fo] = f2bf(v - bf2f(h));
                }
            }
        }
        // pad: cols 112..127 (ks=3, lanes 32..63) zero for this m
        for (int idx = tid; idx < 32; idx += 256) {
            int ln = 32 + idx;
            short8 z = (short8){0, 0, 0, 0, 0, 0, 0, 0};
            size_t fo = ((size_t)m * 4 + 3) * 512 + (size_t)ln * 8;
            *(short8*)&mhB[fo] = z; *(short8*)&mlB[fo] = z;
        }
    } else {
        const int hb = blk - 448;            // 0..383 = i*3 + m
        const int i = hb / 3, m = hb % 3;
        const ushortt* base = ivb + (size_t)i * 3 * 24 * 512;
        ushortt* hhB = hh + (size_t)i * 3 * 2 * 512;
        ushortt* hlB = hl + (size_t)i * 3 * 2 * 512;
        if (wv < 3) {
            int n = wv;
            f32x4 c = (f32x4){0.f, 0.f, 0.f, 0.f};
            for (int dc32 = 0; dc32 < 24; ++dc32) {
                short8 av = *(const short8*)&base[((size_t)m * 24 + dc32) * 512 + lane * 8];
                short8 bv = *(const short8*)&base[((size_t)n * 24 + dc32) * 512 + lane * 8];
                c = __builtin_amdgcn_mfma_f32_16x16x32_bf16(av, bv, c, 0, 0, 0);
            }
#pragma unroll
            for (int reg = 0; reg < 4; ++reg) {
                int rc = n * 16 + l15;                 // col (0..47)
                int lrow = quad * 4 + reg;             // row%16 (tile m)
                float v = c[reg];
                ushortt h = f2bf(v);
                size_t fo = ((size_t)m * 2 + (rc >> 5)) * 512
                          + ((((rc >> 3) & 3) * 16 + lrow) * 8) + (rc & 7);
                hhB[fo] = h;
                hlB[fo] = f2bf(v - bf2f(h));
            }
        }
        // pad: cols 48..63 (ks=1, lanes 32..63) zero for this m
        for (int idx = tid; idx < 32; idx += 256) {
            int ln = 32 + idx;
            short8 z = (short8){0, 0, 0, 0, 0, 0, 0, 0};
            size_t fo = ((size_t)m * 2 + 1) * 512 + (size_t)ln * 8;
            *(short8*)&hhB[fo] = z; *(short8*)&hlB[fo] = z;
        }
    }
}

// ======================= fused kernel (fast path) ========================
// unchanged from r9 (measured best 502us): r7 structure (1-deep K prefetch,
// Y operands in place) + S1==1 algebraic simplification.
__global__ __launch_bounds__(256, 2)
void nafs_fused3(const int*  __restrict__ tlen,
                 const float* __restrict__ ws,
                 const ushortt* __restrict__ khi, const ushortt* __restrict__ klo,
                 const ushortt* __restrict__ qhi, const ushortt* __restrict__ qlo,
                 const ushortt* __restrict__ tvb, const ushortt* __restrict__ ivb,
                 const ushortt* __restrict__ mh, const ushortt* __restrict__ ml,
                 const ushortt* __restrict__ hh, const ushortt* __restrict__ hl,
                 float* __restrict__ out) {
    __shared__ __align__(16) ushortt shATT[48 * 128];   // attn bf16, XOR-swizzled
    __shared__ __align__(16) ushortt shATT2[112 * 64];  // attn2 bf16, XOR-swizzled
    __shared__ __align__(16) ushortt shQ[2 * 9 * 512];  // Q-side frag dbuf (18KB)
    __shared__ float sCol[NR], sSe1[NR], sS21[NR];
    __shared__ float sCos1[NR], sCos2[112];
    __shared__ float sSS1[NR], sDD1[NR], sSS2[112], sDD2[112];

    const int tid  = threadIdx.x;
    const int wv   = tid >> 6;
    const int lane = tid & 63;
    const int quad = lane >> 4;
    const int l15  = lane & 15;
    const int key  = l15 & 7;
    // XCD-aware bijective (t,i) map: xcd = b&7 owns i in [16*xcd, 16*xcd+16)
    const int b    = blockIdx.x;
    const int xcd  = b & 7;
    const int idx  = b >> 3;           // 0..1023
    const int st   = idx >> 6;         // 0..15
    const int rem  = idx & 63;
    const int i    = (xcd << 4) | (rem >> 2);
    const int t    = (st << 2) | (rem & 3);
    const int L    = tlen[t];
    const float Lf = (float)L;

    const float* __restrict__ nVi = ws + 12544;
    const float* __restrict__ nVt = ws + 18688;

    if (tid < NR) {
        sSS1[tid] = 0.f; sDD1[tid] = 0.f;
        sCol[tid] = 0.f; sSe1[tid] = 0.f; sS21[tid] = 0.f;
    }
    // zero the swizzled pad col-blocks r=48..63 of shATT2 (never written later)
    for (int idx2 = tid; idx2 < 112 * 2; idx2 += 256) {
        int w = idx2 >> 1, nb = 6 + (idx2 & 1);
        short8 z = (short8){0, 0, 0, 0, 0, 0, 0, 0};
        *(short8*)&shATT2[w * 64 + ((nb ^ (w & 7)) << 3)] = z;
    }

    // ------- Phase 1: sim (3-pass split bf16) + G = TVB@IVB^T, one K-loop
    const int m0  = wv, m1 = wv + 4;
    const int m1c = (m1 == 7) ? 6 : m1;    // wave3 loads dup tile-6 (discarded)
    const size_t kb0 = ((size_t)(t * 7 + m0)) * 24 * 512 + (size_t)lane * 8;
    const size_t kb1 = ((size_t)(t * 7 + m1c)) * 24 * 512 + (size_t)lane * 8;
    const size_t qb  = ((size_t)(i * 3)) * 24 * 512 + (size_t)lane * 8;
    const ushortt* fK0h = khi + kb0;
    const ushortt* fK0l = klo + kb0;
    const ushortt* fK1h = khi + kb1;
    const ushortt* fK1l = klo + kb1;
    const ushortt* fQh  = qhi + qb;
    const ushortt* fQl  = qlo + qb;
    const ushortt* fA0  = tvb + kb0;
    const ushortt* fA1  = tvb + kb1;
    const ushortt* fB   = ivb + qb;

    f32x4 acc[2][3];
    f32x4 gf[2][3];
#pragma unroll
    for (int a = 0; a < 2; ++a)
#pragma unroll
        for (int n = 0; n < 3; ++n) {
            acc[a][n] = (f32x4){0.f, 0.f, 0.f, 0.f};
            gf[a][n]  = (f32x4){0.f, 0.f, 0.f, 0.f};
        }

    // K-side current regs (prologue: dc32=0)
    short8 c0h = *(const short8*)(fK0h);
    short8 c0l = *(const short8*)(fK0l);
    short8 c1h = *(const short8*)(fK1h);
    short8 c1l = *(const short8*)(fK1l);
    short8 ct0 = *(const short8*)(fA0);
    short8 ct1 = *(const short8*)(fA1);
    // prologue: stage Q(0) into shQ buf0 (frags: 0=b0h 1=b0l 2=b1h 3=b1l
    // 4=b2h 5=b2l 6=tB0 7=tB1 8=tB2; wave w stages frags {w, w+4, (w==0)*8})
    {
        ushortt* dst = shQ + lane * 8;
        if (wv == 0) {
            *(short8*)(dst + 0 * 512) = *(const short8*)(fQh);
            *(short8*)(dst + 4 * 512) = *(const short8*)(fQh + 24576);
            *(short8*)(dst + 8 * 512) = *(const short8*)(fB + 24576);
        } else if (wv == 1) {
            *(short8*)(dst + 1 * 512) = *(const short8*)(fQl);
            *(short8*)(dst + 5 * 512) = *(const short8*)(fQl + 24576);
        } else if (wv == 2) {
            *(short8*)(dst + 2 * 512) = *(const short8*)(fQh + 12288);
            *(short8*)(dst + 6 * 512) = *(const short8*)(fB);
        } else {
            *(short8*)(dst + 3 * 512) = *(const short8*)(fQl + 12288);
            *(short8*)(dst + 7 * 512) = *(const short8*)(fB + 12288);
        }
    }
    __syncthreads();   // init + Q(0) staged

    for (int dc32 = 0; dc32 < 24; ++dc32) {
        const int bb = dc32 & 1;
        short8 n0h, n0l, n1h, n1l, nt0, nt1;   // K prefetch (next iter)
        short8 s0, s1, s2;                     // Q stage values (next iter)
        if (dc32 < 23) {
            const int o = (dc32 + 1) * 512;
            // issue K prefetch (per-wave unique)
            n0h = *(const short8*)(fK0h + o);
            n0l = *(const short8*)(fK0l + o);
            n1h = *(const short8*)(fK1h + o);
            n1l = *(const short8*)(fK1l + o);
            nt0 = *(const short8*)(fA0 + o);
            nt1 = *(const short8*)(fA1 + o);
            // issue Q stage loads (shared side, split across waves)
            if (wv == 0) {
                s0 = *(const short8*)(fQh + o);
                s1 = *(const short8*)(fQh + 24576 + o);
                s2 = *(const short8*)(fB + 24576 + o);
            } else if (wv == 1) {
                s0 = *(const short8*)(fQl + o);
                s1 = *(const short8*)(fQl + 24576 + o);
            } else if (wv == 2) {
                s0 = *(const short8*)(fQh + 12288 + o);
                s1 = *(const short8*)(fB + o);
            } else {
                s0 = *(const short8*)(fQl + 12288 + o);
                s1 = *(const short8*)(fB + 12288 + o);
            }
        }
        // consume current Q frags from LDS, grouped by n (3 ds_reads + 8 MFMAs)
        {
            const ushortt* qs = shQ + bb * (9 * 512) + lane * 8;
#pragma unroll
            for (int n = 0; n < 3; ++n) {
                short8 bh = *(const short8*)(qs + (2 * n) * 512);
                short8 bl = *(const short8*)(qs + (2 * n + 1) * 512);
                short8 tB = *(const short8*)(qs + (6 + n) * 512);
                acc[0][n] = __builtin_amdgcn_mfma_f32_16x16x32_bf16(c0h, bh, acc[0][n], 0, 0, 0);
                acc[0][n] = __builtin_amdgcn_mfma_f32_16x16x32_bf16(c0h, bl, acc[0][n], 0, 0, 0);
                acc[0][n] = __builtin_amdgcn_mfma_f32_16x16x32_bf16(c0l, bh, acc[0][n], 0, 0, 0);
                acc[1][n] = __builtin_amdgcn_mfma_f32_16x16x32_bf16(c1h, bh, acc[1][n], 0, 0, 0);
                acc[1][n] = __builtin_amdgcn_mfma_f32_16x16x32_bf16(c1h, bl, acc[1][n], 0, 0, 0);
                acc[1][n] = __builtin_amdgcn_mfma_f32_16x16x32_bf16(c1l, bh, acc[1][n], 0, 0, 0);
                gf[0][n]  = __builtin_amdgcn_mfma_f32_16x16x32_bf16(ct0, tB, gf[0][n], 0, 0, 0);
                gf[1][n]  = __builtin_amdgcn_mfma_f32_16x16x32_bf16(ct1, tB, gf[1][n], 0, 0, 0);
            }
        }
        if (dc32 < 23) {
            // write staged Q values (vmcnt for s* satisfied under the MFMAs)
            ushortt* dst = shQ + (bb ^ 1) * (9 * 512) + lane * 8;
            if (wv == 0) {
                *(short8*)(dst + 0 * 512) = s0;
                *(short8*)(dst + 4 * 512) = s1;
                *(short8*)(dst + 8 * 512) = s2;
            } else if (wv == 1) {
                *(short8*)(dst + 1 * 512) = s0;
                *(short8*)(dst + 5 * 512) = s1;
            } else if (wv == 2) {
                *(short8*)(dst + 2 * 512) = s0;
                *(short8*)(dst + 6 * 512) = s1;
            } else {
                *(short8*)(dst + 3 * 512) = s0;
                *(short8*)(dst + 7 * 512) = s1;
            }
            c0h = n0h; c0l = n0l; c1h = n1h; c1l = n1l; ct0 = nt0; ct1 = nt1;
        }
        __syncthreads();   // next buf staged; all reads of old buf done
    }

    // ------- Phase 2: in-register softmax (no aT LDS staging) ------------
    // element map: w = m*16 + quad*4 + reg (m = wv + 4a), r = n*16 + l15
    float lk[2][3][4];
#pragma unroll
    for (int a = 0; a < 2; ++a) {
        int m = wv + 4 * a;
        bool ok = (m < 7);
#pragma unroll
        for (int n = 0; n < 3; ++n)
#pragma unroll
            for (int reg = 0; reg < 4; ++reg) {
                float s = ok ? acc[a][n][reg] : 0.f;
                lk[a][n][reg] = (s > 0.f) ? s : 0.1f * s;
            }
    }

    // per-w inverse row norm over r: local over n + xor-reduce over l15
    float invW[2][4];
#pragma unroll
    for (int a = 0; a < 2; ++a)
#pragma unroll
        for (int reg = 0; reg < 4; ++reg) {
            float ss = 0.f;
#pragma unroll
            for (int n = 0; n < 3; ++n) ss = fmaf(lk[a][n][reg], lk[a][n][reg], ss);
            ss += __shfl_xor(ss, 1, 64); ss += __shfl_xor(ss, 2, 64);
            ss += __shfl_xor(ss, 4, 64); ss += __shfl_xor(ss, 8, 64);
            invW[a][reg] = 1.0f / (sqrtf(ss) + EPS);
        }

    // col-norm partials (masked w<L) + branch-1 exp + its denominator partials
    float e1[2][3][4];
    {
        float cs[3] = {0.f, 0.f, 0.f}, es[3] = {0.f, 0.f, 0.f};
#pragma unroll
        for (int a = 0; a < 2; ++a) {
            int m = wv + 4 * a;
#pragma unroll
            for (int reg = 0; reg < 4; ++reg) {
                int w = m * 16 + quad * 4 + reg;
                bool act = (m < 7) && (w < L);
#pragma unroll
                for (int n = 0; n < 3; ++n) {
                    float v = lk[a][n][reg];
                    float e = act ? __expf(v * invW[a][reg] * LAMB) : 0.f;
                    e1[a][n][reg] = e;
                    if (act) cs[n] = fmaf(v, v, cs[n]);
                    es[n] += e;
                }
            }
        }
#pragma unroll
        for (int n = 0; n < 3; ++n) {
            float c = cs[n], e = es[n];
            c += __shfl_xor(c, 16, 64); c += __shfl_xor(c, 32, 64);
            e += __shfl_xor(e, 16, 64); e += __shfl_xor(e, 32, 64);
            if (quad == 0) {
                atomicAdd(&sCol[n * 16 + l15], c);
                atomicAdd(&sSe1[n * 16 + l15], e);
            }
        }
    }
    __syncthreads();   // sCol, sSe1 complete

    // branch-2 (softmax over r per row w) — fully in-wave; S1 == 1 exactly
    {
        float inv2[3];
#pragma unroll
        for (int n = 0; n < 3; ++n) inv2[n] = 1.0f / (sqrtf(sCol[n * 16 + l15]) + EPS);
#pragma unroll
        for (int a = 0; a < 2; ++a) {
            int m = wv + 4 * a;
            if (m < 7) {
#pragma unroll
                for (int reg = 0; reg < 4; ++reg) {
                    int w = m * 16 + quad * 4 + reg;
                    float e2[3];
                    float se = 0.f;
#pragma unroll
                    for (int n = 0; n < 3; ++n) {
                        float e = __expf(lk[a][n][reg] * inv2[n] * LAMB);
                        e2[n] = e; se += e;
                    }
                    se += __shfl_xor(se, 1, 64); se += __shfl_xor(se, 2, 64);
                    se += __shfl_xor(se, 4, 64); se += __shfl_xor(se, 8, 64);
                    float inv = 1.0f / se;
                    float sel[3];
                    float S2 = 0.f;
#pragma unroll
                    for (int n = 0; n < 3; ++n) {
                        float p = e2[n] * inv;
                        sel[n] = ((p * 48.0f - 1.0f) > 0.f) ? p : 0.f;
                        S2 += sel[n];
                    }
                    S2 += __shfl_xor(S2, 1, 64); S2 += __shfl_xor(S2, 2, 64);
                    S2 += __shfl_xor(S2, 4, 64); S2 += __shfl_xor(S2, 8, 64);
                    float iS2 = 1.0f / ((S2 > 0.f) ? S2 : 1.0f);
                    bool rowOK = (w < L);
#pragma unroll
                    for (int n = 0; n < 3; ++n) {
                        float val = rowOK ? sel[n] * iS2 : 0.f;
                        shATT2[swzATT2(w, n * 16 + l15)] = f2bf(val);
                    }
                }
            }
        }
    }

    // branch-1 S2 pass (S1 == 1 exactly; no separate S1 pass needed)
    float invSe[3];
#pragma unroll
    for (int n = 0; n < 3; ++n) invSe[n] = 1.0f / sSe1[n * 16 + l15];
    {
        float s2p[3] = {0.f, 0.f, 0.f};
#pragma unroll
        for (int n = 0; n < 3; ++n) {
#pragma unroll
            for (int a = 0; a < 2; ++a)
#pragma unroll
                for (int reg = 0; reg < 4; ++reg) {
                    float p = e1[a][n][reg] * invSe[n];
                    s2p[n] += ((p * Lf - 1.0f) > 0.f) ? p : 0.f;
                }
        }
#pragma unroll
        for (int n = 0; n < 3; ++n) {
            float v = s2p[n];
            v += __shfl_xor(v, 16, 64); v += __shfl_xor(v, 32, 64);
            if (quad == 0) atomicAdd(&sS21[n * 16 + l15], v);
        }
    }
    __syncthreads();   // sS21 complete

    // branch-1 write: 4 consecutive w per (a,n) -> one packed ushort4 store
    {
#pragma unroll
        for (int n = 0; n < 3; ++n) {
            int r = n * 16 + l15;
            float s2  = sS21[r];
            float iS2 = 1.0f / ((s2 > 0.f) ? s2 : 1.0f);
#pragma unroll
            for (int a = 0; a < 2; ++a) {
                int m = wv + 4 * a;          // m==7 (wave3/a1): e1==0 -> writes zeros (pads cols 112..127)
                ushortt v4[4];
#pragma unroll
                for (int reg = 0; reg < 4; ++reg) {
                    float p  = e1[a][n][reg] * invSe[n];
                    float tm = ((p * Lf - 1.0f) > 0.f) ? p : 0.f;
                    v4[reg] = f2bf(tm * iS2);
                }
                int wb = m * 16 + quad * 4;
                int f  = (((wb >> 3) ^ (r & 7)) << 3) | (wb & 7);
                *(ushort4*)&shATT[r * 128 + f] = *(ushort4*)v4;
            }
        }
    }
    __syncthreads();

    // ---- G epilogue (gf held from merged loop): dd2 (direct), dd1 (atomic)
    {
        float pd1[3] = {0.f, 0.f, 0.f};
#pragma unroll
        for (int a = 0; a < 2; ++a) {
            int m = wv + 4 * a;
            if (m < 7) {
#pragma unroll
                for (int reg = 0; reg < 4; ++reg) {
                    int w = m * 16 + quad * 4 + reg;
                    float p2 = 0.f;
#pragma unroll
                    for (int n = 0; n < 3; ++n) {
                        int r = n * 16 + l15;
                        float gv = gf[a][n][reg];
                        p2 = fmaf(gv, bf2f(shATT2[swzATT2(w, r)]), p2);
                        pd1[n] = fmaf(gv, bf2f(shATT[swzATT(r, w)]), pd1[n]);
                    }
                    p2 += __shfl_xor(p2, 1, 64); p2 += __shfl_xor(p2, 2, 64);
                    p2 += __shfl_xor(p2, 4, 64); p2 += __shfl_xor(p2, 8, 64);
                    if (l15 == 0) sDD2[w] = p2;
                }
            }
        }
#pragma unroll
        for (int n = 0; n < 3; ++n) {
            float p = pd1[n];
            p += __shfl_xor(p, 16, 64); p += __shfl_xor(p, 32, 64);
            if (quad == 0) atomicAdd(&sDD1[n * 16 + l15], p);
        }
    }

    // ---------------- Y-GEMM: Y = attn @ M^T, ss1 ------------------------
    {
        short8 af[3][4];
#pragma unroll
        for (int mt = 0; mt < 3; ++mt)
#pragma unroll
            for (int ks = 0; ks < 4; ++ks)
                af[mt][ks] = *(const short8*)&shATT[(mt * 16 + l15) * 128 + (((ks * 4 + quad) ^ key) << 3)];
        float ps[3][4];
#pragma unroll
        for (int mt = 0; mt < 3; ++mt)
#pragma unroll
            for (int reg = 0; reg < 4; ++reg) ps[mt][reg] = 0.f;
#pragma unroll
        for (int p = 0; p < 2; ++p) {
            int nt = wv + 4 * p;
            if (nt < 7) {
                const ushortt* pMh = mh + ((size_t)(t * 7 + nt)) * 4 * 512 + (size_t)lane * 8;
                const ushortt* pMl = ml + ((size_t)(t * 7 + nt)) * 4 * 512 + (size_t)lane * 8;
                short8 bh[4], bl[4];
#pragma unroll
                for (int ks = 0; ks < 4; ++ks) {
                    bh[ks] = *(const short8*)(pMh + ks * 512);
                    bl[ks] = *(const short8*)(pMl + ks * 512);
                }
                f32x4 y[3];
#pragma unroll
                for (int mt = 0; mt < 3; ++mt) y[mt] = (f32x4){0.f, 0.f, 0.f, 0.f};
#pragma unroll
                for (int mt = 0; mt < 3; ++mt)
#pragma unroll
                    for (int ks = 0; ks < 4; ++ks) {
                        y[mt] = __builtin_amdgcn_mfma_f32_16x16x32_bf16(af[mt][ks], bh[ks], y[mt], 0, 0, 0);
                        y[mt] = __builtin_amdgcn_mfma_f32_16x16x32_bf16(af[mt][ks], bl[ks], y[mt], 0, 0, 0);
                    }
                int wc = nt * 16 + l15;
#pragma unroll
                for (int mt = 0; mt < 3; ++mt)
#pragma unroll
                    for (int reg = 0; reg < 4; ++reg) {
                        int r = mt * 16 + quad * 4 + reg;
                        ps[mt][reg] = fmaf(y[mt][reg], bf2f(shATT[swzATT(r, wc)]), ps[mt][reg]);
                    }
            }
        }
#pragma unroll
        for (int mt = 0; mt < 3; ++mt)
#pragma unroll
            for (int reg = 0; reg < 4; ++reg) {
                float p = ps[mt][reg];
                p += __shfl_xor(p, 1, 64); p += __shfl_xor(p, 2, 64);
                p += __shfl_xor(p, 4, 64); p += __shfl_xor(p, 8, 64);
                if (l15 == 0) atomicAdd(&sSS1[mt * 16 + quad * 4 + reg], p);
            }
    }

    // ---------------- Z-GEMM: Z = attn2 @ H^T, ss2 -----------------------
    {
        short8 zbh[3][2], zbl[3][2];
#pragma unroll
        for (int n = 0; n < 3; ++n) {
#pragma unroll
            for (int ks = 0; ks < 2; ++ks) {
                size_t fo = (((size_t)(i * 3 + n)) * 2 + ks) * 512 + (size_t)lane * 8;
                zbh[n][ks] = *(const short8*)&hh[fo];
                zbl[n][ks] = *(const short8*)&hl[fo];
            }
        }
#pragma unroll
        for (int a = 0; a < 2; ++a) {
            int m = wv + 4 * a;
            if (m < 7) {
                f32x4 z[3];
#pragma unroll
                for (int n = 0; n < 3; ++n) z[n] = (f32x4){0.f, 0.f, 0.f, 0.f};
#pragma unroll
                for (int ks = 0; ks < 2; ++ks) {
                    short8 a2f = *(const short8*)&shATT2[(m * 16 + l15) * 64 + (((ks * 4 + quad) ^ key) << 3)];
#pragma unroll
                    for (int n = 0; n < 3; ++n) {
                        z[n] = __builtin_amdgcn_mfma_f32_16x16x32_bf16(a2f, zbh[n][ks], z[n], 0, 0, 0);
                        z[n] = __builtin_amdgcn_mfma_f32_16x16x32_bf16(a2f, zbl[n][ks], z[n], 0, 0, 0);
                    }
                }
#pragma unroll
                for (int reg = 0; reg < 4; ++reg) {
                    int w = m * 16 + quad * 4 + reg;
                    float p = 0.f;
#pragma unroll
                    for (int n = 0; n < 3; ++n)
                        p = fmaf(z[n][reg], bf2f(shATT2[swzATT2(w, n * 16 + l15)]), p);
                    p += __shfl_xor(p, 1, 64); p += __shfl_xor(p, 2, 64);
                    p += __shfl_xor(p, 4, 64); p += __shfl_xor(p, 8, 64);
                    if (l15 == 0) sSS2[w] = p;
                }
            }
        }
    }
    __syncthreads();

    // ---------------- cosine epilogue + output ---------------------------
    if (tid < NR) {
        float s = fmaxf(sSS1[tid], 0.f), d = sDD1[tid];
        float nu  = sqrtf(s);
        float num = d / (nu + EPS);
        float den = fmaxf(nVi[i * NR + tid] * (nu / (nu + EPS)), EPS);
        sCos1[tid] = num / den;
    } else if (tid >= 64 && tid < 176) {
        int w = tid - 64;
        if (w < L) {
            float s = fmaxf(sSS2[w], 0.f), d = sDD2[w];
            float nu  = sqrtf(s);
            float num = d / (nu + EPS);
            float den = fmaxf(nVt[t * NW + w] * (nu / (nu + EPS)), EPS);
            sCos2[w] = num / den;
        }
    }
    __syncthreads();
    if (tid == 0) {
        float s = 0.f;
        for (int r = 0; r < NR; ++r) s += sCos1[r];
        out[i * NT + t] = s * (1.0f / 48.0f);
    } else if (tid == 64) {
        float s = 0.f;
        for (int w = 0; w < L; ++w) s += sCos2[w];
        out[NI * NT + i * NT + t] = s / Lf;
    }
}

// ======================= fallback (ws too small) =========================
#define A_KH   0
#define A_KL   4480
#define A_QH   8960
#define A_QL   10880
#define A_ATT  0
#define A_ATT2 6528
#define SHA_SZ 14592
#define B1_TVT 3200
#define B2_IVT 6656
#define SHB_SZ 4900

__global__ __launch_bounds__(256, 3)
void nafs_fused_fb(const float* __restrict__ imgQ,
                   const float* __restrict__ imgV,
                   const float* __restrict__ txtK,
                   const float* __restrict__ txtV,
                   const int*  __restrict__ tlen,
                   const float* __restrict__ ws,
                   float* __restrict__ out) {
    __shared__ ushortt shA[SHA_SZ];
    __shared__ float shB[SHB_SZ];
    __shared__ float sKs[NW], sQs[NR], sInvW[NW], sInv2[NR], sCos1[NR], sCos2[112];

    const int tid  = threadIdx.x;
    const int wv   = tid >> 6;
    const int lane = tid & 63;
    const int quad = lane >> 4;
    const int l15  = lane & 15;
    const int b    = blockIdx.x;
    const int t    = b >> 7;
    const int i    = b & 127;
    const int L    = tlen[t];
    const float Lf = (float)L;

    const float* __restrict__ invQ = ws;
    const float* __restrict__ invK = ws + 6144;
    const float* __restrict__ nVi  = ws + 12544;
    const float* __restrict__ nVt  = ws + 18688;

    const float* Kbase  = txtK + (size_t)t * (NW * ND);
    const float* Qbase  = imgQ + (size_t)i * (NR * ND);
    const float* TVbase = txtV + (size_t)t * (NW * ND);
    const float* IVbase = imgV + (size_t)i * (NR * ND);

    if (tid < NW)                  sKs[tid]       = invK[t * NW + tid];
    else if (tid < NW + NR)        sQs[tid - NW]  = invQ[i * NR + (tid - NW)];

    const int mt0 = wv * 2, mt1 = wv * 2 + 1;
    f32x4 acc[2][3];
#pragma unroll
    for (int a = 0; a < 2; ++a)
#pragma unroll
        for (int n = 0; n < 3; ++n) acc[a][n] = (f32x4){0.f, 0.f, 0.f, 0.f};

    for (int dc = 0; dc < ND; dc += 32) {
        __syncthreads();
        for (int idx = tid; idx < 112 * 8; idx += 256) {
            int w = idx >> 3, seg = idx & 7;
            float4 v;
            if (w < NW) {
                v = *(const float4*)(Kbase + (size_t)w * ND + dc + seg * 4);
                float s = sKs[w];
                v.x *= s; v.y *= s; v.z *= s; v.w *= s;
            } else { v.x = v.y = v.z = v.w = 0.f; }
            split_store(v, &shA[A_KH + w * 40 + seg * 4], &shA[A_KL + w * 40 + seg * 4]);
        }
        for (int idx = tid; idx < NR * 8; idx += 256) {
            int r = idx >> 3, seg = idx & 7;
            float4 v = *(const float4*)(Qbase + (size_t)r * ND + dc + seg * 4);
            float s = sQs[r];
            v.x *= s; v.y *= s; v.z *= s; v.w *= s;
            split_store(v, &shA[A_QH + r * 40 + seg * 4], &shA[A_QL + r * 40 + seg * 4]);
        }
        __syncthreads();
        short8 bh[3], bl[3];
#pragma unroll
        for (int n = 0; n < 3; ++n) {
            bh[n] = *(const short8*)&shA[A_QH + (n * 16 + l15) * 40 + quad * 8];
            bl[n] = *(const short8*)&shA[A_QL + (n * 16 + l15) * 40 + quad * 8];
        }
#pragma unroll
        for (int a = 0; a < 2; ++a) {
            int m = (a == 0) ? mt0 : mt1;
            if (m < 7) {
                short8 ah = *(const short8*)&shA[A_KH + (m * 16 + l15) * 40 + quad * 8];
                short8 al = *(const short8*)&shA[A_KL + (m * 16 + l15) * 40 + quad * 8];
#pragma unroll
                for (int n = 0; n < 3; ++n) {
                    acc[a][n] = __builtin_amdgcn_mfma_f32_16x16x32_bf16(ah, bh[n], acc[a][n], 0, 0, 0);
                    acc[a][n] = __builtin_amdgcn_mfma_f32_16x16x32_bf16(ah, bl[n], acc[a][n], 0, 0, 0);
                    acc[a][n] = __builtin_amdgcn_mfma_f32_16x16x32_bf16(al, bh[n], acc[a][n], 0, 0, 0);
                }
            }
        }
    }
    __syncthreads();
#pragma unroll
    for (int a = 0; a < 2; ++a) {
        int m = (a == 0) ? mt0 : mt1;
        if (m < 7) {
#pragma unroll
            for (int n = 0; n < 3; ++n)
#pragma unroll
                for (int reg = 0; reg < 4; ++reg) {
                    int w = m * 16 + quad * 4 + reg;
                    if (w < NW) {
                        float s = acc[a][n][reg];
                        shB[w * 49 + n * 16 + l15] = (s > 0.f) ? s : 0.1f * s;
                    }
                }
        }
    }
    __syncthreads();

    if (tid < NW) {
        float ssum = 0.f;
#pragma unroll 8
        for (int r = 0; r < NR; ++r) { float v = shB[tid * 49 + r]; ssum += v * v; }
        sInvW[tid] = 1.0f / (sqrtf(ssum) + EPS);
    } else if (tid >= 128 && tid < 128 + NR) {
        int r = tid - 128;
        float ssum = 0.f;
        for (int w = 0; w < L; ++w) { float v = shB[w * 49 + r]; ssum += v * v; }
        sInv2[r] = 1.0f / (sqrtf(ssum) + EPS);
    }
    __syncthreads();

    for (int r = wv; r < NR; r += 4) {
        int w1 = lane, w2 = lane + 64;
        int v1ok = (w1 < L), v2ok = (w2 < L);
        float v1 = v1ok ? shB[w1 * 49 + r] * sInvW[w1] * LAMB : -1e30f;
        float v2 = v2ok ? shB[w2 * 49 + r] * sInvW[w2] * LAMB : -1e30f;
        float m  = wredmax(fmaxf(v1, v2));
        float e1 = v1ok ? expf(v1 - m) : 0.f;
        float e2 = v2ok ? expf(v2 - m) : 0.f;
        float inv = 1.0f / wredsum(e1 + e2);
        float p1 = e1 * inv, p2 = e2 * inv;
        float S1 = wredsum(p1 + p2);
        float t1 = ((p1 * Lf - S1) > 0.f) ? p1 : 0.f;
        float t2 = ((p2 * Lf - S1) > 0.f) ? p2 : 0.f;
        float S2 = wredsum(t1 + t2);
        float iS2 = 1.0f / ((S2 > 0.f) ? S2 : 1.0f);
        shA[A_ATT + r * 136 + w1] = f2bf(t1 * iS2);
        shA[A_ATT + r * 136 + w2] = f2bf(t2 * iS2);
    }
    for (int w = wv; w < L; w += 4) {
        int rok = (lane < NR);
        float v = rok ? shB[w * 49 + lane] * sInv2[lane] * LAMB : -1e30f;
        float m = wredmax(v);
        float e = rok ? expf(v - m) : 0.f;
        float inv = 1.0f / wredsum(e);
        float p = e * inv;
        float S1 = wredsum(p);
        float tm = ((p * 48.0f - S1) > 0.f) ? p : 0.f;
        float S2 = wredsum(tm);
        float iS2 = 1.0f / ((S2 > 0.f) ? S2 : 1.0f);
        shA[A_ATT2 + w * 72 + lane] = f2bf(tm * iS2);
    }
    for (int w = L + wv; w < 112; w += 4) shA[A_ATT2 + w * 72 + lane] = 0;
    __syncthreads();

    ushortt* shBu = (ushortt*)shB;
    const int kk = (L + 31) >> 5;
    float ss1[4] = {0.f, 0.f, 0.f, 0.f}, dd1[4] = {0.f, 0.f, 0.f, 0.f};
    const int mt = wv;
    const int cgrp = tid >> 5, ccol = tid & 31;

    for (int cc = 0; cc < ND; cc += 32) {
        __syncthreads();
        for (int w = cgrp; w < 128; w += 8) {
            float val = (w < NW) ? TVbase[(size_t)w * ND + cc + ccol] : 0.f;
            shBu[B1_TVT + ccol * 136 + w] = f2bf(val);
        }
        for (int idx = tid; idx < NR * 8; idx += 256) {
            int r = idx >> 3, seg = idx & 7;
            float4 v = *(const float4*)(IVbase + (size_t)r * ND + cc + seg * 4);
            float* p = &shB[r * 33 + seg * 4];
            p[0] = v.x; p[1] = v.y; p[2] = v.z; p[3] = v.w;
        }
        __syncthreads();
        if (mt < 3) {
            f32x4 u[2] = {(f32x4){0.f,0.f,0.f,0.f}, (f32x4){0.f,0.f,0.f,0.f}};
            for (int ks = 0; ks < kk; ++ks) {
                short8 a = *(const short8*)&shA[A_ATT + (mt * 16 + l15) * 136 + ks * 32 + quad * 8];
#pragma unroll
                for (int n = 0; n < 2; ++n) {
                    short8 bb = *(const short8*)&shBu[B1_TVT + (n * 16 + l15) * 136 + ks * 32 + quad * 8];
                    u[n] = __builtin_amdgcn_mfma_f32_16x16x32_bf16(a, bb, u[n], 0, 0, 0);
                }
            }
#pragma unroll
            for (int n = 0; n < 2; ++n)
#pragma unroll
                for (int reg = 0; reg < 4; ++reg) {
                    int r = mt * 16 + quad * 4 + reg;
                    float uu = u[n][reg];
                    ss1[reg] = fmaf(uu, uu, ss1[reg]);
                    dd1[reg] = fmaf(uu, shB[r * 33 + n * 16 + l15], dd1[reg]);
                }
        }
    }
    if (mt < 3) {
#pragma unroll
        for (int reg = 0; reg < 4; ++reg) {
            float s = ss1[reg], d = dd1[reg];
#pragma unroll
            for (int m = 1; m < 16; m <<= 1) { s += __shfl_xor(s, m, 64); d += __shfl_xor(d, m, 64); }
            if (l15 == 0) {
                int r = mt * 16 + quad * 4 + reg;
                float nu  = sqrtf(s);
                float num = d / (nu + EPS);
                float den = fmaxf(nVi[i * NR + r] * (nu / (nu + EPS)), EPS);
                sCos1[r] = num / den;
            }
        }
    }

    const int ntot = (L + 15) >> 4;
    float ss2[2] = {0.f, 0.f}, dd2[2] = {0.f, 0.f};

    for (int cc = 0; cc < ND; cc += 32) {
        __syncthreads();
        for (int idx = tid; idx < NW * 8; idx += 256) {
            int w = idx >> 3, seg = idx & 7;
            float4 v = *(const float4*)(TVbase + (size_t)w * ND + cc + seg * 4);
            float* p = &shB[w * 33 + seg * 4];
            p[0] = v.x; p[1] = v.y; p[2] = v.z; p[3] = v.w;
        }
        for (int r = cgrp; r < 64; r += 8) {
            float val = (r < NR) ? IVbase[(size_t)r * ND + cc + ccol] : 0.f;
            shBu[B2_IVT + ccol * 72 + r] = f2bf(val);
        }
        __syncthreads();
#pragma unroll
        for (int pp = 0; pp < 2; ++pp) {
            int nt = wv + 4 * pp;
            if (nt < ntot) {
                f32x4 u[2] = {(f32x4){0.f,0.f,0.f,0.f}, (f32x4){0.f,0.f,0.f,0.f}};
#pragma unroll
                for (int ks = 0; ks < 2; ++ks) {
                    short8 bb = *(const short8*)&shA[A_ATT2 + (nt * 16 + l15) * 72 + ks * 32 + quad * 8];
#pragma unroll
                    for (int mm = 0; mm < 2; ++mm) {
                        short8 aa = *(const short8*)&shBu[B2_IVT + (mm * 16 + l15) * 72 + ks * 32 + quad * 8];
                        u[mm] = __builtin_amdgcn_mfma_f32_16x16x32_bf16(aa, bb, u[mm], 0, 0, 0);
                    }
                }
                int w = nt * 16 + l15;
                float tvok = (w < L) ? 1.f : 0.f;
#pragma unroll
                for (int mm = 0; mm < 2; ++mm)
#pragma unroll
                    for (int reg = 0; reg < 4; ++reg) {
                        int c = mm * 16 + quad * 4 + reg;
                        float uu = u[mm][reg];
                        float tv = (w < L) ? shB[w * 33 + c] : 0.f;
                        ss2[pp] = fmaf(uu, uu, ss2[pp]);
                        dd2[pp] = fmaf(uu, tv * tvok, dd2[pp]);
                    }
            }
        }
    }
#pragma unroll
    for (int pp = 0; pp < 2; ++pp) {
        int nt = wv + 4 * pp;
        if (nt < ntot) {
            float s = ss2[pp], d = dd2[pp];
            s += __shfl_xor(s, 16, 64); d += __shfl_xor(d, 16, 64);
            s += __shfl_xor(s, 32, 64); d += __shfl_xor(d, 32, 64);
            if (quad == 0) {
                int w = nt * 16 + l15;
                if (w < L) {
                    float nu  = sqrtf(s);
                    float num = d / (nu + EPS);
                    float den = fmaxf(nVt[t * NW + w] * (nu / (nu + EPS)), EPS);
                    sCos2[w] = num / den;
                }
            }
        }
    }
    __syncthreads();
    if (tid == 0) {
        float s = 0.f;
        for (int r = 0; r < NR; ++r) s += sCos1[r];
        out[i * NT + t] = s * (1.0f / 48.0f);
    } else if (tid == 64) {
        float s = 0.f;
        for (int w = 0; w < L; ++w) s += sCos2[w];
        out[NI * NT + i * NT + t] = s / Lf;
    }
}

extern "C" void kernel_launch(void* const* d_in, const int* in_sizes, int n_in,
                              void* d_out, int out_size, void* d_ws, size_t ws_size,
                              hipStream_t stream) {
    (void)in_sizes; (void)n_in; (void)out_size;
    const float* imgQ = (const float*)d_in[0];
    const float* imgV = (const float*)d_in[1];
    const float* txtK = (const float*)d_in[2];
    const float* txtV = (const float*)d_in[3];
    const int*   tlen = (const int*)d_in[4];
    float* ws  = (float*)d_ws;
    float* out = (float*)d_out;

    hipLaunchKernelGGL(nafs_norms, dim3(6272), dim3(256), 0, stream,
                       imgQ, imgV, txtK, txtV, ws);

    if (ws_size >= WS_NEED) {
        char* base = (char*)d_ws;
        ushortt* khi = (ushortt*)(base + OFF_KHI);
        ushortt* klo = (ushortt*)(base + OFF_KLO);
        ushortt* qhi = (ushortt*)(base + OFF_QHI);
        ushortt* qlo = (ushortt*)(base + OFF_QLO);
        ushortt* tvb = (ushortt*)(base + OFF_TVB);
        ushortt* ivb = (ushortt*)(base + OFF_IVB);
        ushortt* mh  = (ushortt*)(base + OFF_MH);
        ushortt* ml  = (ushortt*)(base + OFF_ML);
        ushortt* hh  = (ushortt*)(base + OFF_HH);
        ushortt* hl  = (ushortt*)(base + OFF_HL);
        hipLaunchKernelGGL(nafs_convert, dim3(1664), dim3(256), 0, stream,
                           txtK, imgQ, txtV, imgV, ws, khi, klo, qhi, qlo, tvb, ivb);
        hipLaunchKernelGGL(nafs_gram, dim3(832), dim3(256), 0, stream,
                           tvb, ivb, mh, ml, hh, hl);
        hipLaunchKernelGGL(nafs_fused3, dim3(NT * NI), dim3(256), 0, stream,
                           tlen, ws, khi, klo, qhi, qlo, tvb, ivb, mh, ml, hh, hl, out);
    } else {
        hipLaunchKernelGGL(nafs_fused_fb, dim3(NT * NI), dim3(256), 0, stream,
                           imgQ, imgV, txtK, txtV, tlen, ws, out);
    }
}

// Round 11
// 592.935 us; speedup vs baseline: 1.0477x; 1.0477x over previous
//
#include <hip/hip_runtime.h>

#define EPS   1e-8f
#define LAMB  20.0f
#define NI    128
#define NR    48
#define NT    64
#define NW    100
#define ND    768

typedef unsigned int uint;
typedef unsigned short ushortt;
typedef __attribute__((ext_vector_type(8))) short short8;
typedef __attribute__((ext_vector_type(4))) float f32x4;

// ======================= ws layout (fast path) ===========================
// All big arrays are stored in MFMA *fragment order*:
//   frag[tile][dc32][lane][8]  (lane = quad*16 + l15; 512 ushorts per dc32)
// element (row, col) of the logical [rows][ND] matrix lives at
//   ((tile)*NC + col/32)*512 + (((col%32)/8)*16 + row%16)*8 + col%8
// so a wave's fragment load is base + lane*16 bytes: fully coalesced 1KB.
// floats: [0,6144) invQ, [6144,12544) invK, [12544,18688) nVi, [18688,25088) nVt
#define OFF_KHI  102400ULL      // bf16 frag [64][7][24][512] normalized K hi
#define OFF_KLO  11112448ULL
#define OFF_QHI  22122496ULL    // bf16 frag [128][3][24][512] normalized Q hi
#define OFF_QLO  31559680ULL
#define OFF_TVB  40996864ULL    // bf16 frag [64][7][24][512] TV rows
#define OFF_IVB  52006912ULL    // bf16 frag [128][3][24][512] IV rows
#define OFF_MH   61444096ULL    // bf16 frag [64][7][4][512] M=TV.TV^T hi (k-pad zero)
#define OFF_ML   63279104ULL
#define OFF_HH   65114112ULL    // bf16 frag [128][3][2][512] H=IV.IV^T hi (k-pad zero)
#define OFF_HL   65900544ULL
#define WS_NEED  66686976ULL

__device__ inline unsigned short f2bf(float f) {
    uint u = __float_as_uint(f);
    u = (u + 0x7fffu + ((u >> 16) & 1u)) >> 16;
    return (unsigned short)u;
}
__device__ inline float bf2f(unsigned short h) {
    return __uint_as_float((uint)h << 16);
}
__device__ inline void split_store(float4 v, ushortt* hp, ushortt* lp) {
    unsigned short h0 = f2bf(v.x), h1 = f2bf(v.y), h2 = f2bf(v.z), h3 = f2bf(v.w);
    float f0 = bf2f(h0), f1 = bf2f(h1), f2 = bf2f(h2), f3 = bf2f(h3);
    ushort4 H; H.x = h0; H.y = h1; H.z = h2; H.w = h3;
    ushort4 L2; L2.x = f2bf(v.x - f0); L2.y = f2bf(v.y - f1); L2.z = f2bf(v.z - f2); L2.w = f2bf(v.w - f3);
    *(ushort4*)hp = H;
    *(ushort4*)lp = L2;
}
// swizzled LDS element addresses (16B-block XOR swizzle)
__device__ inline int swzATT(int r, int w) {   // shATT[48][128]
    return r * 128 + ((((w >> 3) ^ (r & 7)) << 3) | (w & 7));
}
__device__ inline int swzATT2(int w, int r) {  // shATT2[112][64]
    return w * 64 + ((((r >> 3) ^ (w & 7)) << 3) | (r & 7));
}
__device__ inline float wredsum(float v) {
#pragma unroll
    for (int m = 1; m < 64; m <<= 1) v += __shfl_xor(v, m, 64);
    return v;
}
__device__ inline float wredmax(float v) {
#pragma unroll
    for (int m = 1; m < 64; m <<= 1) v = fmaxf(v, __shfl_xor(v, m, 64));
    return v;
}

// ======================= prep kernels ====================================
__global__ void nafs_norms(const float* __restrict__ imgQ,
                           const float* __restrict__ imgV,
                           const float* __restrict__ txtK,
                           const float* __restrict__ txtV,
                           float* __restrict__ ws) {
    int row  = blockIdx.x * 4 + (threadIdx.x >> 6);
    int lane = threadIdx.x & 63;
    const float* src;
    int inv;
    if (row < 6144)       { src = imgQ + (size_t)row * ND;           inv = 1; }
    else if (row < 12544) { src = txtK + (size_t)(row - 6144) * ND;  inv = 1; }
    else if (row < 18688) { src = imgV + (size_t)(row - 12544) * ND; inv = 0; }
    else                  { src = txtV + (size_t)(row - 18688) * ND; inv = 0; }
    float ss = 0.f;
#pragma unroll
    for (int j = 0; j < 3; ++j) {
        float4 v = *(const float4*)(src + j * 256 + lane * 4);
        ss += v.x * v.x + v.y * v.y + v.z * v.z + v.w * v.w;
    }
#pragma unroll
    for (int off = 32; off > 0; off >>= 1) ss += __shfl_down(ss, off, 64);
    if (lane == 0) {
        float n = sqrtf(ss);
        ws[row] = inv ? (1.0f / (n + EPS)) : n;
    }
}

// convert: one block = one 16-row tile; coalesced reads -> LDS fragment
// transpose -> contiguous 16B stores.
__global__ __launch_bounds__(256)
void nafs_convert(const float* __restrict__ txtK,
                  const float* __restrict__ imgQ,
                  const float* __restrict__ txtV,
                  const float* __restrict__ imgV,
                  const float* __restrict__ ws,
                  ushortt* __restrict__ khi, ushortt* __restrict__ klo,
                  ushortt* __restrict__ qhi, ushortt* __restrict__ qlo,
                  ushortt* __restrict__ tvb, ushortt* __restrict__ ivb) {
    __shared__ __align__(16) ushortt sH[24 * 512];
    __shared__ __align__(16) ushortt sL[24 * 512];
    const int blk = blockIdx.x;
    const int tid = threadIdx.x;

    const float* src;
    const float* scale = nullptr;   // per-row scale (K/Q) or null
    ushortt* dh;
    ushortt* dl = nullptr;          // lo output (K/Q) or null
    int rowbase, rowlimit;

    if (blk < 448) {                      // K: t*7+m
        int tile = blk, t = tile / 7, m = tile % 7;
        src = txtK + (size_t)t * NW * ND;
        scale = ws + 6144 + t * NW;
        dh = khi + (size_t)tile * 24 * 512;
        dl = klo + (size_t)tile * 24 * 512;
        rowbase = m * 16; rowlimit = NW;
    } else if (blk < 832) {               // Q: i*3+n
        int tile = blk - 448, i = tile / 3;
        src = imgQ + (size_t)i * NR * ND;
        scale = ws + i * NR;
        dh = qhi + (size_t)tile * 24 * 512;
        dl = qlo + (size_t)tile * 24 * 512;
        rowbase = (tile % 3) * 16; rowlimit = NR;
    } else if (blk < 1280) {              // TVB
        int tile = blk - 832, t = tile / 7, m = tile % 7;
        src = txtV + (size_t)t * NW * ND;
        dh = tvb + (size_t)tile * 24 * 512;
        rowbase = m * 16; rowlimit = NW;
    } else {                              // IVB
        int tile = blk - 1280, i = tile / 3;
        src = imgV + (size_t)i * NR * ND;
        dh = ivb + (size_t)tile * 24 * 512;
        rowbase = (tile % 3) * 16; rowlimit = NR;
    }

    // stage 1: 16 rows x 192 float4 = 3072 units, 12 per thread, coalesced reads
#pragma unroll
    for (int j = 0; j < 12; ++j) {
        int idx = tid + j * 256;          // 0..3071
        int l   = idx / 192;              // row within tile 0..15
        int c4  = idx % 192;              // float4 index within row
        int row = rowbase + l;
        int dc32 = c4 >> 3, quad = (c4 & 7) >> 1, j0 = (c4 & 1) * 4;
        int off  = dc32 * 512 + (quad * 16 + l) * 8 + j0;
        if (row < rowlimit) {
            float4 v = *(const float4*)(src + (size_t)row * ND + c4 * 4);
            if (scale) { float s = scale[row]; v.x *= s; v.y *= s; v.z *= s; v.w *= s; }
            if (dl) {
                split_store(v, &sH[off], &sL[off]);
            } else {
                ushort4 u; u.x = f2bf(v.x); u.y = f2bf(v.y); u.z = f2bf(v.z); u.w = f2bf(v.w);
                *(ushort4*)&sH[off] = u;
            }
        } else {
            ushort4 z; z.x = z.y = z.z = z.w = 0;
            *(ushort4*)&sH[off] = z;
            if (dl) *(ushort4*)&sL[off] = z;
        }
    }
    __syncthreads();
    // stage 2: contiguous 16B stores (1536 short8 units, 6 per thread)
#pragma unroll
    for (int j = 0; j < 6; ++j) {
        int idx = tid + j * 256;
        *(short8*)&dh[idx * 8] = *(short8*)&sH[idx * 8];
        if (dl) *(short8*)&dl[idx * 8] = *(short8*)&sL[idx * 8];
    }
}

// M[t] = TVB @ TVB^T -> bf16 hi/lo fragment order (k-pad zero); 448 blocks.
__global__ void nafs_gram_m(const ushortt* __restrict__ tvb,
                            ushortt* __restrict__ mh, ushortt* __restrict__ ml) {
    const int blk = blockIdx.x;          // 448 = t*7+m
    const int t = blk / 7, m = blk % 7;
    const int tid = threadIdx.x, wv = tid >> 6, lane = tid & 63;
    const int quad = lane >> 4, l15 = lane & 15;
    const ushortt* base = tvb + (size_t)t * 7 * 24 * 512;
    ushortt* mhB = mh + (size_t)t * 7 * 4 * 512;
    ushortt* mlB = ml + (size_t)t * 7 * 4 * 512;

    const int n0 = wv, n1 = wv + 4;
    f32x4 c0 = (f32x4){0.f, 0.f, 0.f, 0.f};
    f32x4 c1 = (f32x4){0.f, 0.f, 0.f, 0.f};
    for (int dc32 = 0; dc32 < 24; ++dc32) {
        short8 av = *(const short8*)&base[((size_t)m * 24 + dc32) * 512 + lane * 8];
        short8 b0 = *(const short8*)&base[((size_t)n0 * 24 + dc32) * 512 + lane * 8];
        c0 = __builtin_amdgcn_mfma_f32_16x16x32_bf16(av, b0, c0, 0, 0, 0);
        if (n1 < 7) {
            short8 b1 = *(const short8*)&base[((size_t)n1 * 24 + dc32) * 512 + lane * 8];
            c1 = __builtin_amdgcn_mfma_f32_16x16x32_bf16(av, b1, c1, 0, 0, 0);
        }
    }
#pragma unroll
    for (int p = 0; p < 2; ++p) {
        int n = (p == 0) ? n0 : n1;
        if (n < 7) {
            f32x4 c = (p == 0) ? c0 : c1;
#pragma unroll
            for (int reg = 0; reg < 4; ++reg) {
                int wc = n * 16 + l15;             // col (0..111)
                int lrow = quad * 4 + reg;         // row%16 within tile m
                float v = c[reg];
                ushortt h = f2bf(v);
                size_t fo = ((size_t)m * 4 + (wc >> 5)) * 512
                          + ((((wc >> 3) & 3) * 16 + lrow) * 8) + (wc & 7);
                mhB[fo] = h;
                mlB[fo] = f2bf(v - bf2f(h));
            }
        }
    }
    // pad: cols 112..127 (ks=3, lanes 32..63) zero for this m
    for (int idx = tid; idx < 32; idx += 256) {
        int ln = 32 + idx;
        short8 z = (short8){0, 0, 0, 0, 0, 0, 0, 0};
        size_t fo = ((size_t)m * 4 + 3) * 512 + (size_t)ln * 8;
        *(short8*)&mhB[fo] = z; *(short8*)&mlB[fo] = z;
    }
}

// H[i] = IVB @ IVB^T -> bf16 hi/lo fragment order (k-pad zero)
__global__ void nafs_gram_h(const ushortt* __restrict__ ivb,
                            ushortt* __restrict__ hh, ushortt* __restrict__ hl) {
    const int i = blockIdx.x;
    const int tid = threadIdx.x, wv = tid >> 6, lane = tid & 63;
    const int quad = lane >> 4, l15 = lane & 15;
    const ushortt* base = ivb + (size_t)i * 3 * 24 * 512;
    ushortt* hhB = hh + (size_t)i * 3 * 2 * 512;
    ushortt* hlB = hl + (size_t)i * 3 * 2 * 512;
    if (wv < 3) {
        int m = wv;
        f32x4 c[3];
#pragma unroll
        for (int n = 0; n < 3; ++n) c[n] = (f32x4){0.f, 0.f, 0.f, 0.f};
        for (int dc32 = 0; dc32 < 24; ++dc32) {
            short8 av = *(const short8*)&base[((size_t)m * 24 + dc32) * 512 + lane * 8];
#pragma unroll
            for (int n = 0; n < 3; ++n) {
                short8 bv = *(const short8*)&base[((size_t)n * 24 + dc32) * 512 + lane * 8];
                c[n] = __builtin_amdgcn_mfma_f32_16x16x32_bf16(av, bv, c[n], 0, 0, 0);
            }
        }
#pragma unroll
        for (int n = 0; n < 3; ++n)
#pragma unroll
            for (int reg = 0; reg < 4; ++reg) {
                int rc = n * 16 + l15;                 // col (0..47)
                int lrow = quad * 4 + reg;             // row%16 (tile m)
                float v = c[n][reg];
                ushortt h = f2bf(v);
                size_t fo = ((size_t)m * 2 + (rc >> 5)) * 512
                          + ((((rc >> 3) & 3) * 16 + lrow) * 8) + (rc & 7);
                hhB[fo] = h;
                hlB[fo] = f2bf(v - bf2f(h));
            }
    }
    // pad: cols 48..63 (ks=1, lanes 32..63) zero for all 3 row-tiles
    for (int idx = tid; idx < 3 * 32; idx += 256) {
        int m = idx >> 5, ln = 32 + (idx & 31);
        short8 z = (short8){0, 0, 0, 0, 0, 0, 0, 0};
        size_t fo = ((size_t)m * 2 + 1) * 512 + (size_t)ln * 8;
        *(short8*)&hhB[fo] = z; *(short8*)&hlB[fo] = z;
    }
}

// ======================= fused kernel (fast path) ========================
// r11 = r9 exactly (measured best 596.2us total / 502us fused3):
// r7 structure (1-deep K prefetch, Y operands in place) + S1==1 algebraic
// simplification. r10's gram fusion regressed (serialized M behind H in one
// dispatch); reverted.
__global__ __launch_bounds__(256, 2)
void nafs_fused3(const int*  __restrict__ tlen,
                 const float* __restrict__ ws,
                 const ushortt* __restrict__ khi, const ushortt* __restrict__ klo,
                 const ushortt* __restrict__ qhi, const ushortt* __restrict__ qlo,
                 const ushortt* __restrict__ tvb, const ushortt* __restrict__ ivb,
                 const ushortt* __restrict__ mh, const ushortt* __restrict__ ml,
                 const ushortt* __restrict__ hh, const ushortt* __restrict__ hl,
                 float* __restrict__ out) {
    __shared__ __align__(16) ushortt shATT[48 * 128];   // attn bf16, XOR-swizzled
    __shared__ __align__(16) ushortt shATT2[112 * 64];  // attn2 bf16, XOR-swizzled
    __shared__ __align__(16) ushortt shQ[2 * 9 * 512];  // Q-side frag dbuf (18KB)
    __shared__ float sCol[NR], sSe1[NR], sS21[NR];
    __shared__ float sCos1[NR], sCos2[112];
    __shared__ float sSS1[NR], sDD1[NR], sSS2[112], sDD2[112];

    const int tid  = threadIdx.x;
    const int wv   = tid >> 6;
    const int lane = tid & 63;
    const int quad = lane >> 4;
    const int l15  = lane & 15;
    const int key  = l15 & 7;
    // XCD-aware bijective (t,i) map: xcd = b&7 owns i in [16*xcd, 16*xcd+16)
    const int b    = blockIdx.x;
    const int xcd  = b & 7;
    const int idx  = b >> 3;           // 0..1023
    const int st   = idx >> 6;         // 0..15
    const int rem  = idx & 63;
    const int i    = (xcd << 4) | (rem >> 2);
    const int t    = (st << 2) | (rem & 3);
    const int L    = tlen[t];
    const float Lf = (float)L;

    const float* __restrict__ nVi = ws + 12544;
    const float* __restrict__ nVt = ws + 18688;

    if (tid < NR) {
        sSS1[tid] = 0.f; sDD1[tid] = 0.f;
        sCol[tid] = 0.f; sSe1[tid] = 0.f; sS21[tid] = 0.f;
    }
    // zero the swizzled pad col-blocks r=48..63 of shATT2 (never written later)
    for (int idx2 = tid; idx2 < 112 * 2; idx2 += 256) {
        int w = idx2 >> 1, nb = 6 + (idx2 & 1);
        short8 z = (short8){0, 0, 0, 0, 0, 0, 0, 0};
        *(short8*)&shATT2[w * 64 + ((nb ^ (w & 7)) << 3)] = z;
    }

    // ------- Phase 1: sim (3-pass split bf16) + G = TVB@IVB^T, one K-loop
    const int m0  = wv, m1 = wv + 4;
    const int m1c = (m1 == 7) ? 6 : m1;    // wave3 loads dup tile-6 (discarded)
    const size_t kb0 = ((size_t)(t * 7 + m0)) * 24 * 512 + (size_t)lane * 8;
    const size_t kb1 = ((size_t)(t * 7 + m1c)) * 24 * 512 + (size_t)lane * 8;
    const size_t qb  = ((size_t)(i * 3)) * 24 * 512 + (size_t)lane * 8;
    const ushortt* fK0h = khi + kb0;
    const ushortt* fK0l = klo + kb0;
    const ushortt* fK1h = khi + kb1;
    const ushortt* fK1l = klo + kb1;
    const ushortt* fQh  = qhi + qb;
    const ushortt* fQl  = qlo + qb;
    const ushortt* fA0  = tvb + kb0;
    const ushortt* fA1  = tvb + kb1;
    const ushortt* fB   = ivb + qb;

    f32x4 acc[2][3];
    f32x4 gf[2][3];
#pragma unroll
    for (int a = 0; a < 2; ++a)
#pragma unroll
        for (int n = 0; n < 3; ++n) {
            acc[a][n] = (f32x4){0.f, 0.f, 0.f, 0.f};
            gf[a][n]  = (f32x4){0.f, 0.f, 0.f, 0.f};
        }

    // K-side current regs (prologue: dc32=0)
    short8 c0h = *(const short8*)(fK0h);
    short8 c0l = *(const short8*)(fK0l);
    short8 c1h = *(const short8*)(fK1h);
    short8 c1l = *(const short8*)(fK1l);
    short8 ct0 = *(const short8*)(fA0);
    short8 ct1 = *(const short8*)(fA1);
    // prologue: stage Q(0) into shQ buf0 (frags: 0=b0h 1=b0l 2=b1h 3=b1l
    // 4=b2h 5=b2l 6=tB0 7=tB1 8=tB2; wave w stages frags {w, w+4, (w==0)*8})
    {
        ushortt* dst = shQ + lane * 8;
        if (wv == 0) {
            *(short8*)(dst + 0 * 512) = *(const short8*)(fQh);
            *(short8*)(dst + 4 * 512) = *(const short8*)(fQh + 24576);
            *(short8*)(dst + 8 * 512) = *(const short8*)(fB + 24576);
        } else if (wv == 1) {
            *(short8*)(dst + 1 * 512) = *(const short8*)(fQl);
            *(short8*)(dst + 5 * 512) = *(const short8*)(fQl + 24576);
        } else if (wv == 2) {
            *(short8*)(dst + 2 * 512) = *(const short8*)(fQh + 12288);
            *(short8*)(dst + 6 * 512) = *(const short8*)(fB);
        } else {
            *(short8*)(dst + 3 * 512) = *(const short8*)(fQl + 12288);
            *(short8*)(dst + 7 * 512) = *(const short8*)(fB + 12288);
        }
    }
    __syncthreads();   // init + Q(0) staged

    for (int dc32 = 0; dc32 < 24; ++dc32) {
        const int bb = dc32 & 1;
        short8 n0h, n0l, n1h, n1l, nt0, nt1;   // K prefetch (next iter)
        short8 s0, s1, s2;                     // Q stage values (next iter)
        if (dc32 < 23) {
            const int o = (dc32 + 1) * 512;
            // issue K prefetch (per-wave unique)
            n0h = *(const short8*)(fK0h + o);
            n0l = *(const short8*)(fK0l + o);
            n1h = *(const short8*)(fK1h + o);
            n1l = *(const short8*)(fK1l + o);
            nt0 = *(const short8*)(fA0 + o);
            nt1 = *(const short8*)(fA1 + o);
            // issue Q stage loads (shared side, split across waves)
            if (wv == 0) {
                s0 = *(const short8*)(fQh + o);
                s1 = *(const short8*)(fQh + 24576 + o);
                s2 = *(const short8*)(fB + 24576 + o);
            } else if (wv == 1) {
                s0 = *(const short8*)(fQl + o);
                s1 = *(const short8*)(fQl + 24576 + o);
            } else if (wv == 2) {
                s0 = *(const short8*)(fQh + 12288 + o);
                s1 = *(const short8*)(fB + o);
            } else {
                s0 = *(const short8*)(fQl + 12288 + o);
                s1 = *(const short8*)(fB + 12288 + o);
            }
        }
        // consume current Q frags from LDS, grouped by n (3 ds_reads + 8 MFMAs)
        {
            const ushortt* qs = shQ + bb * (9 * 512) + lane * 8;
#pragma unroll
            for (int n = 0; n < 3; ++n) {
                short8 bh = *(const short8*)(qs + (2 * n) * 512);
                short8 bl = *(const short8*)(qs + (2 * n + 1) * 512);
                short8 tB = *(const short8*)(qs + (6 + n) * 512);
                acc[0][n] = __builtin_amdgcn_mfma_f32_16x16x32_bf16(c0h, bh, acc[0][n], 0, 0, 0);
                acc[0][n] = __builtin_amdgcn_mfma_f32_16x16x32_bf16(c0h, bl, acc[0][n], 0, 0, 0);
                acc[0][n] = __builtin_amdgcn_mfma_f32_16x16x32_bf16(c0l, bh, acc[0][n], 0, 0, 0);
                acc[1][n] = __builtin_amdgcn_mfma_f32_16x16x32_bf16(c1h, bh, acc[1][n], 0, 0, 0);
                acc[1][n] = __builtin_amdgcn_mfma_f32_16x16x32_bf16(c1h, bl, acc[1][n], 0, 0, 0);
                acc[1][n] = __builtin_amdgcn_mfma_f32_16x16x32_bf16(c1l, bh, acc[1][n], 0, 0, 0);
                gf[0][n]  = __builtin_amdgcn_mfma_f32_16x16x32_bf16(ct0, tB, gf[0][n], 0, 0, 0);
                gf[1][n]  = __builtin_amdgcn_mfma_f32_16x16x32_bf16(ct1, tB, gf[1][n], 0, 0, 0);
            }
        }
        if (dc32 < 23) {
            // write staged Q values (vmcnt for s* satisfied under the MFMAs)
            ushortt* dst = shQ + (bb ^ 1) * (9 * 512) + lane * 8;
            if (wv == 0) {
                *(short8*)(dst + 0 * 512) = s0;
                *(short8*)(dst + 4 * 512) = s1;
                *(short8*)(dst + 8 * 512) = s2;
            } else if (wv == 1) {
                *(short8*)(dst + 1 * 512) = s0;
                *(short8*)(dst + 5 * 512) = s1;
            } else if (wv == 2) {
                *(short8*)(dst + 2 * 512) = s0;
                *(short8*)(dst + 6 * 512) = s1;
            } else {
                *(short8*)(dst + 3 * 512) = s0;
                *(short8*)(dst + 7 * 512) = s1;
            }
            c0h = n0h; c0l = n0l; c1h = n1h; c1l = n1l; ct0 = nt0; ct1 = nt1;
        }
        __syncthreads();   // next buf staged; all reads of old buf done
    }

    // ------- Phase 2: in-register softmax (no aT LDS staging) ------------
    // element map: w = m*16 + quad*4 + reg (m = wv + 4a), r = n*16 + l15
    float lk[2][3][4];
#pragma unroll
    for (int a = 0; a < 2; ++a) {
        int m = wv + 4 * a;
        bool ok = (m < 7);
#pragma unroll
        for (int n = 0; n < 3; ++n)
#pragma unroll
            for (int reg = 0; reg < 4; ++reg) {
                float s = ok ? acc[a][n][reg] : 0.f;
                lk[a][n][reg] = (s > 0.f) ? s : 0.1f * s;
            }
    }

    // per-w inverse row norm over r: local over n + xor-reduce over l15
    float invW[2][4];
#pragma unroll
    for (int a = 0; a < 2; ++a)
#pragma unroll
        for (int reg = 0; reg < 4; ++reg) {
            float ss = 0.f;
#pragma unroll
            for (int n = 0; n < 3; ++n) ss = fmaf(lk[a][n][reg], lk[a][n][reg], ss);
            ss += __shfl_xor(ss, 1, 64); ss += __shfl_xor(ss, 2, 64);
            ss += __shfl_xor(ss, 4, 64); ss += __shfl_xor(ss, 8, 64);
            invW[a][reg] = 1.0f / (sqrtf(ss) + EPS);
        }

    // col-norm partials (masked w<L) + branch-1 exp + its denominator partials
    float e1[2][3][4];
    {
        float cs[3] = {0.f, 0.f, 0.f}, es[3] = {0.f, 0.f, 0.f};
#pragma unroll
        for (int a = 0; a < 2; ++a) {
            int m = wv + 4 * a;
#pragma unroll
            for (int reg = 0; reg < 4; ++reg) {
                int w = m * 16 + quad * 4 + reg;
                bool act = (m < 7) && (w < L);
#pragma unroll
                for (int n = 0; n < 3; ++n) {
                    float v = lk[a][n][reg];
                    float e = act ? __expf(v * invW[a][reg] * LAMB) : 0.f;
                    e1[a][n][reg] = e;
                    if (act) cs[n] = fmaf(v, v, cs[n]);
                    es[n] += e;
                }
            }
        }
#pragma unroll
        for (int n = 0; n < 3; ++n) {
            float c = cs[n], e = es[n];
            c += __shfl_xor(c, 16, 64); c += __shfl_xor(c, 32, 64);
            e += __shfl_xor(e, 16, 64); e += __shfl_xor(e, 32, 64);
            if (quad == 0) {
                atomicAdd(&sCol[n * 16 + l15], c);
                atomicAdd(&sSe1[n * 16 + l15], e);
            }
        }
    }
    __syncthreads();   // sCol, sSe1 complete

    // branch-2 (softmax over r per row w) — fully in-wave; S1 == 1 exactly
    {
        float inv2[3];
#pragma unroll
        for (int n = 0; n < 3; ++n) inv2[n] = 1.0f / (sqrtf(sCol[n * 16 + l15]) + EPS);
#pragma unroll
        for (int a = 0; a < 2; ++a) {
            int m = wv + 4 * a;
            if (m < 7) {
#pragma unroll
                for (int reg = 0; reg < 4; ++reg) {
                    int w = m * 16 + quad * 4 + reg;
                    float e2[3];
                    float se = 0.f;
#pragma unroll
                    for (int n = 0; n < 3; ++n) {
                        float e = __expf(lk[a][n][reg] * inv2[n] * LAMB);
                        e2[n] = e; se += e;
                    }
                    se += __shfl_xor(se, 1, 64); se += __shfl_xor(se, 2, 64);
                    se += __shfl_xor(se, 4, 64); se += __shfl_xor(se, 8, 64);
                    float inv = 1.0f / se;
                    float sel[3];
                    float S2 = 0.f;
#pragma unroll
                    for (int n = 0; n < 3; ++n) {
                        float p = e2[n] * inv;
                        sel[n] = ((p * 48.0f - 1.0f) > 0.f) ? p : 0.f;
                        S2 += sel[n];
                    }
                    S2 += __shfl_xor(S2, 1, 64); S2 += __shfl_xor(S2, 2, 64);
                    S2 += __shfl_xor(S2, 4, 64); S2 += __shfl_xor(S2, 8, 64);
                    float iS2 = 1.0f / ((S2 > 0.f) ? S2 : 1.0f);
                    bool rowOK = (w < L);
#pragma unroll
                    for (int n = 0; n < 3; ++n) {
                        float val = rowOK ? sel[n] * iS2 : 0.f;
                        shATT2[swzATT2(w, n * 16 + l15)] = f2bf(val);
                    }
                }
            }
        }
    }

    // branch-1 S2 pass (S1 == 1 exactly; no separate S1 pass needed)
    float invSe[3];
#pragma unroll
    for (int n = 0; n < 3; ++n) invSe[n] = 1.0f / sSe1[n * 16 + l15];
    {
        float s2p[3] = {0.f, 0.f, 0.f};
#pragma unroll
        for (int n = 0; n < 3; ++n) {
#pragma unroll
            for (int a = 0; a < 2; ++a)
#pragma unroll
                for (int reg = 0; reg < 4; ++reg) {
                    float p = e1[a][n][reg] * invSe[n];
                    s2p[n] += ((p * Lf - 1.0f) > 0.f) ? p : 0.f;
                }
        }
#pragma unroll
        for (int n = 0; n < 3; ++n) {
            float v = s2p[n];
            v += __shfl_xor(v, 16, 64); v += __shfl_xor(v, 32, 64);
            if (quad == 0) atomicAdd(&sS21[n * 16 + l15], v);
        }
    }
    __syncthreads();   // sS21 complete

    // branch-1 write: 4 consecutive w per (a,n) -> one packed ushort4 store
    {
#pragma unroll
        for (int n = 0; n < 3; ++n) {
            int r = n * 16 + l15;
            float s2  = sS21[r];
            float iS2 = 1.0f / ((s2 > 0.f) ? s2 : 1.0f);
#pragma unroll
            for (int a = 0; a < 2; ++a) {
                int m = wv + 4 * a;          // m==7 (wave3/a1): e1==0 -> writes zeros (pads cols 112..127)
                ushortt v4[4];
#pragma unroll
                for (int reg = 0; reg < 4; ++reg) {
                    float p  = e1[a][n][reg] * invSe[n];
                    float tm = ((p * Lf - 1.0f) > 0.f) ? p : 0.f;
                    v4[reg] = f2bf(tm * iS2);
                }
                int wb = m * 16 + quad * 4;
                int f  = (((wb >> 3) ^ (r & 7)) << 3) | (wb & 7);
                *(ushort4*)&shATT[r * 128 + f] = *(ushort4*)v4;
            }
        }
    }
    __syncthreads();

    // ---- G epilogue (gf held from merged loop): dd2 (direct), dd1 (atomic)
    {
        float pd1[3] = {0.f, 0.f, 0.f};
#pragma unroll
        for (int a = 0; a < 2; ++a) {
            int m = wv + 4 * a;
            if (m < 7) {
#pragma unroll
                for (int reg = 0; reg < 4; ++reg) {
                    int w = m * 16 + quad * 4 + reg;
                    float p2 = 0.f;
#pragma unroll
                    for (int n = 0; n < 3; ++n) {
                        int r = n * 16 + l15;
                        float gv = gf[a][n][reg];
                        p2 = fmaf(gv, bf2f(shATT2[swzATT2(w, r)]), p2);
                        pd1[n] = fmaf(gv, bf2f(shATT[swzATT(r, w)]), pd1[n]);
                    }
                    p2 += __shfl_xor(p2, 1, 64); p2 += __shfl_xor(p2, 2, 64);
                    p2 += __shfl_xor(p2, 4, 64); p2 += __shfl_xor(p2, 8, 64);
                    if (l15 == 0) sDD2[w] = p2;
                }
            }
        }
#pragma unroll
        for (int n = 0; n < 3; ++n) {
            float p = pd1[n];
            p += __shfl_xor(p, 16, 64); p += __shfl_xor(p, 32, 64);
            if (quad == 0) atomicAdd(&sDD1[n * 16 + l15], p);
        }
    }

    // ---------------- Y-GEMM: Y = attn @ M^T, ss1 ------------------------
    {
        short8 af[3][4];
#pragma unroll
        for (int mt = 0; mt < 3; ++mt)
#pragma unroll
            for (int ks = 0; ks < 4; ++ks)
                af[mt][ks] = *(const short8*)&shATT[(mt * 16 + l15) * 128 + (((ks * 4 + quad) ^ key) << 3)];
        float ps[3][4];
#pragma unroll
        for (int mt = 0; mt < 3; ++mt)
#pragma unroll
            for (int reg = 0; reg < 4; ++reg) ps[mt][reg] = 0.f;
#pragma unroll
        for (int p = 0; p < 2; ++p) {
            int nt = wv + 4 * p;
            if (nt < 7) {
                const ushortt* pMh = mh + ((size_t)(t * 7 + nt)) * 4 * 512 + (size_t)lane * 8;
                const ushortt* pMl = ml + ((size_t)(t * 7 + nt)) * 4 * 512 + (size_t)lane * 8;
                short8 bh[4], bl[4];
#pragma unroll
                for (int ks = 0; ks < 4; ++ks) {
                    bh[ks] = *(const short8*)(pMh + ks * 512);
                    bl[ks] = *(const short8*)(pMl + ks * 512);
                }
                f32x4 y[3];
#pragma unroll
                for (int mt = 0; mt < 3; ++mt) y[mt] = (f32x4){0.f, 0.f, 0.f, 0.f};
#pragma unroll
                for (int mt = 0; mt < 3; ++mt)
#pragma unroll
                    for (int ks = 0; ks < 4; ++ks) {
                        y[mt] = __builtin_amdgcn_mfma_f32_16x16x32_bf16(af[mt][ks], bh[ks], y[mt], 0, 0, 0);
                        y[mt] = __builtin_amdgcn_mfma_f32_16x16x32_bf16(af[mt][ks], bl[ks], y[mt], 0, 0, 0);
                    }
                int wc = nt * 16 + l15;
#pragma unroll
                for (int mt = 0; mt < 3; ++mt)
#pragma unroll
                    for (int reg = 0; reg < 4; ++reg) {
                        int r = mt * 16 + quad * 4 + reg;
                        ps[mt][reg] = fmaf(y[mt][reg], bf2f(shATT[swzATT(r, wc)]), ps[mt][reg]);
                    }
            }
        }
#pragma unroll
        for (int mt = 0; mt < 3; ++mt)
#pragma unroll
            for (int reg = 0; reg < 4; ++reg) {
                float p = ps[mt][reg];
                p += __shfl_xor(p, 1, 64); p += __shfl_xor(p, 2, 64);
                p += __shfl_xor(p, 4, 64); p += __shfl_xor(p, 8, 64);
                if (l15 == 0) atomicAdd(&sSS1[mt * 16 + quad * 4 + reg], p);
            }
    }

    // ---------------- Z-GEMM: Z = attn2 @ H^T, ss2 -----------------------
    {
        short8 zbh[3][2], zbl[3][2];
#pragma unroll
        for (int n = 0; n < 3; ++n) {
#pragma unroll
            for (int ks = 0; ks < 2; ++ks) {
                size_t fo = (((size_t)(i * 3 + n)) * 2 + ks) * 512 + (size_t)lane * 8;
                zbh[n][ks] = *(const short8*)&hh[fo];
                zbl[n][ks] = *(const short8*)&hl[fo];
            }
        }
#pragma unroll
        for (int a = 0; a < 2; ++a) {
            int m = wv + 4 * a;
            if (m < 7) {
                f32x4 z[3];
#pragma unroll
                for (int n = 0; n < 3; ++n) z[n] = (f32x4){0.f, 0.f, 0.f, 0.f};
#pragma unroll
                for (int ks = 0; ks < 2; ++ks) {
                    short8 a2f = *(const short8*)&shATT2[(m * 16 + l15) * 64 + (((ks * 4 + quad) ^ key) << 3)];
#pragma unroll
                    for (int n = 0; n < 3; ++n) {
                        z[n] = __builtin_amdgcn_mfma_f32_16x16x32_bf16(a2f, zbh[n][ks], z[n], 0, 0, 0);
                        z[n] = __builtin_amdgcn_mfma_f32_16x16x32_bf16(a2f, zbl[n][ks], z[n], 0, 0, 0);
                    }
                }
#pragma unroll
                for (int reg = 0; reg < 4; ++reg) {
                    int w = m * 16 + quad * 4 + reg;
                    float p = 0.f;
#pragma unroll
                    for (int n = 0; n < 3; ++n)
                        p = fmaf(z[n][reg], bf2f(shATT2[swzATT2(w, n * 16 + l15)]), p);
                    p += __shfl_xor(p, 1, 64); p += __shfl_xor(p, 2, 64);
                    p += __shfl_xor(p, 4, 64); p += __shfl_xor(p, 8, 64);
                    if (l15 == 0) sSS2[w] = p;
                }
            }
        }
    }
    __syncthreads();

    // ---------------- cosine epilogue + output ---------------------------
    if (tid < NR) {
        float s = fmaxf(sSS1[tid], 0.f), d = sDD1[tid];
        float nu  = sqrtf(s);
        float num = d / (nu + EPS);
        float den = fmaxf(nVi[i * NR + tid] * (nu / (nu + EPS)), EPS);
        sCos1[tid] = num / den;
    } else if (tid >= 64 && tid < 176) {
        int w = tid - 64;
        if (w < L) {
            float s = fmaxf(sSS2[w], 0.f), d = sDD2[w];
            float nu  = sqrtf(s);
            float num = d / (nu + EPS);
            float den = fmaxf(nVt[t * NW + w] * (nu / (nu + EPS)), EPS);
            sCos2[w] = num / den;
        }
    }
    __syncthreads();
    if (tid == 0) {
        float s = 0.f;
        for (int r = 0; r < NR; ++r) s += sCos1[r];
        out[i * NT + t] = s * (1.0f / 48.0f);
    } else if (tid == 64) {
        float s = 0.f;
        for (int w = 0; w < L; ++w) s += sCos2[w];
        out[NI * NT + i * NT + t] = s / Lf;
    }
}

// ======================= fallback (ws too small) =========================
#define A_KH   0
#define A_KL   4480
#define A_QH   8960
#define A_QL   10880
#define A_ATT  0
#define A_ATT2 6528
#define SHA_SZ 14592
#define B1_TVT 3200
#define B2_IVT 6656
#define SHB_SZ 4900

__global__ __launch_bounds__(256, 3)
void nafs_fused_fb(const float* __restrict__ imgQ,
                   const float* __restrict__ imgV,
                   const float* __restrict__ txtK,
                   const float* __restrict__ txtV,
                   const int*  __restrict__ tlen,
                   const float* __restrict__ ws,
                   float* __restrict__ out) {
    __shared__ ushortt shA[SHA_SZ];
    __shared__ float shB[SHB_SZ];
    __shared__ float sKs[NW], sQs[NR], sInvW[NW], sInv2[NR], sCos1[NR], sCos2[112];

    const int tid  = threadIdx.x;
    const int wv   = tid >> 6;
    const int lane = tid & 63;
    const int quad = lane >> 4;
    const int l15  = lane & 15;
    const int b    = blockIdx.x;
    const int t    = b >> 7;
    const int i    = b & 127;
    const int L    = tlen[t];
    const float Lf = (float)L;

    const float* __restrict__ invQ = ws;
    const float* __restrict__ invK = ws + 6144;
    const float* __restrict__ nVi  = ws + 12544;
    const float* __restrict__ nVt  = ws + 18688;

    const float* Kbase  = txtK + (size_t)t * (NW * ND);
    const float* Qbase  = imgQ + (size_t)i * (NR * ND);
    const float* TVbase = txtV + (size_t)t * (NW * ND);
    const float* IVbase = imgV + (size_t)i * (NR * ND);

    if (tid < NW)                  sKs[tid]       = invK[t * NW + tid];
    else if (tid < NW + NR)        sQs[tid - NW]  = invQ[i * NR + (tid - NW)];

    const int mt0 = wv * 2, mt1 = wv * 2 + 1;
    f32x4 acc[2][3];
#pragma unroll
    for (int a = 0; a < 2; ++a)
#pragma unroll
        for (int n = 0; n < 3; ++n) acc[a][n] = (f32x4){0.f, 0.f, 0.f, 0.f};

    for (int dc = 0; dc < ND; dc += 32) {
        __syncthreads();
        for (int idx = tid; idx < 112 * 8; idx += 256) {
            int w = idx >> 3, seg = idx & 7;
            float4 v;
            if (w < NW) {
                v = *(const float4*)(Kbase + (size_t)w * ND + dc + seg * 4);
                float s = sKs[w];
                v.x *= s; v.y *= s; v.z *= s; v.w *= s;
            } else { v.x = v.y = v.z = v.w = 0.f; }
            split_store(v, &shA[A_KH + w * 40 + seg * 4], &shA[A_KL + w * 40 + seg * 4]);
        }
        for (int idx = tid; idx < NR * 8; idx += 256) {
            int r = idx >> 3, seg = idx & 7;
            float4 v = *(const float4*)(Qbase + (size_t)r * ND + dc + seg * 4);
            float s = sQs[r];
            v.x *= s; v.y *= s; v.z *= s; v.w *= s;
            split_store(v, &shA[A_QH + r * 40 + seg * 4], &shA[A_QL + r * 40 + seg * 4]);
        }
        __syncthreads();
        short8 bh[3], bl[3];
#pragma unroll
        for (int n = 0; n < 3; ++n) {
            bh[n] = *(const short8*)&shA[A_QH + (n * 16 + l15) * 40 + quad * 8];
            bl[n] = *(const short8*)&shA[A_QL + (n * 16 + l15) * 40 + quad * 8];
        }
#pragma unroll
        for (int a = 0; a < 2; ++a) {
            int m = (a == 0) ? mt0 : mt1;
            if (m < 7) {
                short8 ah = *(const short8*)&shA[A_KH + (m * 16 + l15) * 40 + quad * 8];
                short8 al = *(const short8*)&shA[A_KL + (m * 16 + l15) * 40 + quad * 8];
#pragma unroll
                for (int n = 0; n < 3; ++n) {
                    acc[a][n] = __builtin_amdgcn_mfma_f32_16x16x32_bf16(ah, bh[n], acc[a][n], 0, 0, 0);
                    acc[a][n] = __builtin_amdgcn_mfma_f32_16x16x32_bf16(ah, bl[n], acc[a][n], 0, 0, 0);
                    acc[a][n] = __builtin_amdgcn_mfma_f32_16x16x32_bf16(al, bh[n], acc[a][n], 0, 0, 0);
                }
            }
        }
    }
    __syncthreads();
#pragma unroll
    for (int a = 0; a < 2; ++a) {
        int m = (a == 0) ? mt0 : mt1;
        if (m < 7) {
#pragma unroll
            for (int n = 0; n < 3; ++n)
#pragma unroll
                for (int reg = 0; reg < 4; ++reg) {
                    int w = m * 16 + quad * 4 + reg;
                    if (w < NW) {
                        float s = acc[a][n][reg];
                        shB[w * 49 + n * 16 + l15] = (s > 0.f) ? s : 0.1f * s;
                    }
                }
        }
    }
    __syncthreads();

    if (tid < NW) {
        float ssum = 0.f;
#pragma unroll 8
        for (int r = 0; r < NR; ++r) { float v = shB[tid * 49 + r]; ssum += v * v; }
        sInvW[tid] = 1.0f / (sqrtf(ssum) + EPS);
    } else if (tid >= 128 && tid < 128 + NR) {
        int r = tid - 128;
        float ssum = 0.f;
        for (int w = 0; w < L; ++w) { float v = shB[w * 49 + r]; ssum += v * v; }
        sInv2[r] = 1.0f / (sqrtf(ssum) + EPS);
    }
    __syncthreads();

    for (int r = wv; r < NR; r += 4) {
        int w1 = lane, w2 = lane + 64;
        int v1ok = (w1 < L), v2ok = (w2 < L);
        float v1 = v1ok ? shB[w1 * 49 + r] * sInvW[w1] * LAMB : -1e30f;
        float v2 = v2ok ? shB[w2 * 49 + r] * sInvW[w2] * LAMB : -1e30f;
        float m  = wredmax(fmaxf(v1, v2));
        float e1 = v1ok ? expf(v1 - m) : 0.f;
        float e2 = v2ok ? expf(v2 - m) : 0.f;
        float inv = 1.0f / wredsum(e1 + e2);
        float p1 = e1 * inv, p2 = e2 * inv;
        float S1 = wredsum(p1 + p2);
        float t1 = ((p1 * Lf - S1) > 0.f) ? p1 : 0.f;
        float t2 = ((p2 * Lf - S1) > 0.f) ? p2 : 0.f;
        float S2 = wredsum(t1 + t2);
        float iS2 = 1.0f / ((S2 > 0.f) ? S2 : 1.0f);
        shA[A_ATT + r * 136 + w1] = f2bf(t1 * iS2);
        shA[A_ATT + r * 136 + w2] = f2bf(t2 * iS2);
    }
    for (int w = wv; w < L; w += 4) {
        int rok = (lane < NR);
        float v = rok ? shB[w * 49 + lane] * sInv2[lane] * LAMB : -1e30f;
        float m = wredmax(v);
        float e = rok ? expf(v - m) : 0.f;
        float inv = 1.0f / wredsum(e);
        float p = e * inv;
        float S1 = wredsum(p);
        float tm = ((p * 48.0f - S1) > 0.f) ? p : 0.f;
        float S2 = wredsum(tm);
        float iS2 = 1.0f / ((S2 > 0.f) ? S2 : 1.0f);
        shA[A_ATT2 + w * 72 + lane] = f2bf(tm * iS2);
    }
    for (int w = L + wv; w < 112; w += 4) shA[A_ATT2 + w * 72 + lane] = 0;
    __syncthreads();

    ushortt* shBu = (ushortt*)shB;
    const int kk = (L + 31) >> 5;
    float ss1[4] = {0.f, 0.f, 0.f, 0.f}, dd1[4] = {0.f, 0.f, 0.f, 0.f};
    const int mt = wv;
    const int cgrp = tid >> 5, ccol = tid & 31;

    for (int cc = 0; cc < ND; cc += 32) {
        __syncthreads();
        for (int w = cgrp; w < 128; w += 8) {
            float val = (w < NW) ? TVbase[(size_t)w * ND + cc + ccol] : 0.f;
            shBu[B1_TVT + ccol * 136 + w] = f2bf(val);
        }
        for (int idx = tid; idx < NR * 8; idx += 256) {
            int r = idx >> 3, seg = idx & 7;
            float4 v = *(const float4*)(IVbase + (size_t)r * ND + cc + seg * 4);
            float* p = &shB[r * 33 + seg * 4];
            p[0] = v.x; p[1] = v.y; p[2] = v.z; p[3] = v.w;
        }
        __syncthreads();
        if (mt < 3) {
            f32x4 u[2] = {(f32x4){0.f,0.f,0.f,0.f}, (f32x4){0.f,0.f,0.f,0.f}};
            for (int ks = 0; ks < kk; ++ks) {
                short8 a = *(const short8*)&shA[A_ATT + (mt * 16 + l15) * 136 + ks * 32 + quad * 8];
#pragma unroll
                for (int n = 0; n < 2; ++n) {
                    short8 bb = *(const short8*)&shBu[B1_TVT + (n * 16 + l15) * 136 + ks * 32 + quad * 8];
                    u[n] = __builtin_amdgcn_mfma_f32_16x16x32_bf16(a, bb, u[n], 0, 0, 0);
                }
            }
#pragma unroll
            for (int n = 0; n < 2; ++n)
#pragma unroll
                for (int reg = 0; reg < 4; ++reg) {
                    int r = mt * 16 + quad * 4 + reg;
                    float uu = u[n][reg];
                    ss1[reg] = fmaf(uu, uu, ss1[reg]);
                    dd1[reg] = fmaf(uu, shB[r * 33 + n * 16 + l15], dd1[reg]);
                }
        }
    }
    if (mt < 3) {
#pragma unroll
        for (int reg = 0; reg < 4; ++reg) {
            float s = ss1[reg], d = dd1[reg];
#pragma unroll
            for (int m = 1; m < 16; m <<= 1) { s += __shfl_xor(s, m, 64); d += __shfl_xor(d, m, 64); }
            if (l15 == 0) {
                int r = mt * 16 + quad * 4 + reg;
                float nu  = sqrtf(s);
                float num = d / (nu + EPS);
                float den = fmaxf(nVi[i * NR + r] * (nu / (nu + EPS)), EPS);
                sCos1[r] = num / den;
            }
        }
    }

    const int ntot = (L + 15) >> 4;
    float ss2[2] = {0.f, 0.f}, dd2[2] = {0.f, 0.f};

    for (int cc = 0; cc < ND; cc += 32) {
        __syncthreads();
        for (int idx = tid; idx < NW * 8; idx += 256) {
            int w = idx >> 3, seg = idx & 7;
            float4 v = *(const float4*)(TVbase + (size_t)w * ND + cc + seg * 4);
            float* p = &shB[w * 33 + seg * 4];
            p[0] = v.x; p[1] = v.y; p[2] = v.z; p[3] = v.w;
        }
        for (int r = cgrp; r < 64; r += 8) {
            float val = (r < NR) ? IVbase[(size_t)r * ND + cc + ccol] : 0.f;
            shBu[B2_IVT + ccol * 72 + r] = f2bf(val);
        }
        __syncthreads();
#pragma unroll
        for (int pp = 0; pp < 2; ++pp) {
            int nt = wv + 4 * pp;
            if (nt < ntot) {
                f32x4 u[2] = {(f32x4){0.f,0.f,0.f,0.f}, (f32x4){0.f,0.f,0.f,0.f}};
#pragma unroll
                for (int ks = 0; ks < 2; ++ks) {
                    short8 bb = *(const short8*)&shA[A_ATT2 + (nt * 16 + l15) * 72 + ks * 32 + quad * 8];
#pragma unroll
                    for (int mm = 0; mm < 2; ++mm) {
                        short8 aa = *(const short8*)&shBu[B2_IVT + (mm * 16 + l15) * 72 + ks * 32 + quad * 8];
                        u[mm] = __builtin_amdgcn_mfma_f32_16x16x32_bf16(aa, bb, u[mm], 0, 0, 0);
                    }
                }
                int w = nt * 16 + l15;
                float tvok = (w < L) ? 1.f : 0.f;
#pragma unroll
                for (int mm = 0; mm < 2; ++mm)
#pragma unroll
                    for (int reg = 0; reg < 4; ++reg) {
                        int c = mm * 16 + quad * 4 + reg;
                        float uu = u[mm][reg];
                        float tv = (w < L) ? shB[w * 33 + c] : 0.f;
                        ss2[pp] = fmaf(uu, uu, ss2[pp]);
                        dd2[pp] = fmaf(uu, tv * tvok, dd2[pp]);
                    }
            }
        }
    }
#pragma unroll
    for (int pp = 0; pp < 2; ++pp) {
        int nt = wv + 4 * pp;
        if (nt < ntot) {
            float s = ss2[pp], d = dd2[pp];
            s += __shfl_xor(s, 16, 64); d += __shfl_xor(d, 16, 64);
            s += __shfl_xor(s, 32, 64); d += __shfl_xor(d, 32, 64);
            if (quad == 0) {
                int w = nt * 16 + l15;
                if (w < L) {
                    float nu  = sqrtf(s);
                    float num = d / (nu + EPS);
                    float den = fmaxf(nVt[t * NW + w] * (nu / (nu + EPS)), EPS);
                    sCos2[w] = num / den;
                }
            }
        }
    }
    __syncthreads();
    if (tid == 0) {
        float s = 0.f;
        for (int r = 0; r < NR; ++r) s += sCos1[r];
        out[i * NT + t] = s * (1.0f / 48.0f);
    } else if (tid == 64) {
        float s = 0.f;
        for (int w = 0; w < L; ++w) s += sCos2[w];
        out[NI * NT + i * NT + t] = s / Lf;
    }
}

extern "C" void kernel_launch(void* const* d_in, const int* in_sizes, int n_in,
                              void* d_out, int out_size, void* d_ws, size_t ws_size,
                              hipStream_t stream) {
    (void)in_sizes; (void)n_in; (void)out_size;
    const float* imgQ = (const float*)d_in[0];
    const float* imgV = (const float*)d_in[1];
    const float* txtK = (const float*)d_in[2];
    const float* txtV = (const float*)d_in[3];
    const int*   tlen = (const int*)d_in[4];
    float* ws  = (float*)d_ws;
    float* out = (float*)d_out;

    hipLaunchKernelGGL(nafs_norms, dim3(6272), dim3(256), 0, stream,
                       imgQ, imgV, txtK, txtV, ws);

    if (ws_size >= WS_NEED) {
        char* base = (char*)d_ws;
        ushortt* khi = (ushortt*)(base + OFF_KHI);
        ushortt* klo = (ushortt*)(base + OFF_KLO);
        ushortt* qhi = (ushortt*)(base + OFF_QHI);
        ushortt* qlo = (ushortt*)(base + OFF_QLO);
        ushortt* tvb = (ushortt*)(base + OFF_TVB);
        ushortt* ivb = (ushortt*)(base + OFF_IVB);
        ushortt* mh  = (ushortt*)(base + OFF_MH);
        ushortt* ml  = (ushortt*)(base + OFF_ML);
        ushortt* hh  = (ushortt*)(base + OFF_HH);
        ushortt* hl  = (ushortt*)(base + OFF_HL);
        hipLaunchKernelGGL(nafs_convert, dim3(1664), dim3(256), 0, stream,
                           txtK, imgQ, txtV, imgV, ws, khi, klo, qhi, qlo, tvb, ivb);
        hipLaunchKernelGGL(nafs_gram_m, dim3(448), dim3(256), 0, stream, tvb, mh, ml);
        hipLaunchKernelGGL(nafs_gram_h, dim3(128), dim3(256), 0, stream, ivb, hh, hl);
        hipLaunchKernelGGL(nafs_fused3, dim3(NT * NI), dim3(256), 0, stream,
                           tlen, ws, khi, klo, qhi, qlo, tvb, ivb, mh, ml, hh, hl, out);
    } else {
        hipLaunchKernelGGL(nafs_fused_fb, dim3(NT * NI), dim3(256), 0, stream,
                           imgQ, imgV, txtK, txtV, tlen, ws, out);
    }
}